// Round 7
// baseline (306.098 us; speedup 1.0000x reference)
//
#include <hip/hip_runtime.h>
#include <hip/hip_bf16.h>
#include <math.h>

// Differential causal self-attention. ALL I/O float32; internal bf16 MFMA.
// FAST PATH (ws_size >= 40MB): batch-merged launches, 4 dispatches.
//   ws: [0,16M) xb (x as bf16; reused as attn-out after QKV consumes it)
//       [16M,24M) Wq,Wk,Wv,Wproj as bf16 (2MB each)
//       [24M,40M) vt = V transposed per batch: vt[b][dim 0..1023][t 0..2047]
//   d_out: [0,16M) q bf16, [16M,32M) k bf16 (dead before proj writes f32)
// Attention: FIXED-max softmax in base-2 (rmsnorm => |S'|<=11.6, m=9*log2e).
// Round 14: attn micro-opts on the verified round-13 base —
//   * FUSED PV: QK+softmax for both components first (wave-private ps reused
//     serially; compiler orders via lgkmcnt), then ONE PV loop reading each V
//     fragment once for o1+o2. -16 ds_read_b128/step/wave, 32-MFMA cluster.
//     VGPR 96 -> ~110: MUST stay < 128 (round-5 lesson: >128 halves occupancy).
//   * exp2 folding: log2e folded into q-scale (gemm_qkv epilogue) and M_FIX;
//     __expf (mul+v_exp) -> exp2f (bare v_exp). -64 VALU/step/wave. Same math.
// Round 13 (kept): RMSNorm+RoPE fused in gemm_qkv epilogue; diff_attn2 =
//   async gload_lds dbuf K1/K2/V, 1 barrier/k-tile, grid (32,32), 2 blk/CU.
// Round 10 (kept): GEMMs on async gload_lds dbuf, 1 barrier/step, XCD tiles.
// Round 8 (kept): XCD-local bh=blockIdx.x remap (FETCH 125->38MB).
// NO launch_bounds cap: round 7's (256,4) forced VGPR=64 -> spills, 2x regr.
// FALLBACK (small ws): round-4 proven per-batch pipeline, zero ws usage.

typedef __bf16 bf16_t;
typedef __bf16 bf16x8 __attribute__((ext_vector_type(8)));
typedef __bf16 bf16x4 __attribute__((ext_vector_type(4)));
typedef float  f32x4  __attribute__((ext_vector_type(4)));

#define T_SEQ 2048
#define C_EMB 1024
static constexpr float LAMBDA_INIT = 0.6192834728526787f;   // 0.8 - 0.6*exp(-1.2)
static constexpr float ONE_MINUS_LI = 0.3807165271473213f;
static constexpr float RMS_EPS = 1.1920928955078125e-07f;
static constexpr float LN_EPS = 1e-5f;
static constexpr float M_FIX2 = 12.984255368000671f;  // 9 * log2(e): fixed max, base-2
static constexpr float QSCL2  = 0.18033688011112042f; // 0.125 * log2(e)

__device__ __forceinline__ f32x4 mfma16(bf16x8 a, bf16x8 b, f32x4 c) {
  return __builtin_amdgcn_mfma_f32_16x16x32_bf16(a, b, c, 0, 0, 0);
}
__device__ __forceinline__ float declamp(float v, float lim) {
  return fminf(fmaxf(v, -lim), lim);   // IEEE min/max: NaN firewall too
}
// async global->LDS, 16B per lane; lds dest must be wave-uniform base (+lane*16)
__device__ __forceinline__ void ldsload16(const bf16_t* g, bf16_t* l) {
  __builtin_amdgcn_global_load_lds(
      (const __attribute__((address_space(1))) void*)g,
      (__attribute__((address_space(3))) void*)l, 16, 0, 0);
}

// ==================== FAST PATH ====================

// ---- one-shot f32 -> bf16 convert: x (8M) + 4 weights (1M each) ----
__global__ __launch_bounds__(256) void cvt_all(
    const float* __restrict__ x,  const float* __restrict__ Wq,
    const float* __restrict__ Wk, const float* __restrict__ Wv,
    const float* __restrict__ Wp,
    bf16_t* __restrict__ xb,  bf16_t* __restrict__ wqb, bf16_t* __restrict__ wkb,
    bf16_t* __restrict__ wvb, bf16_t* __restrict__ wpb)
{
  size_t i4 = ((size_t)blockIdx.x * 256 + threadIdx.x) * 4;
  const float* s; bf16_t* d; size_t off;
  if      (i4 <  8388608) { s = x;  d = xb;  off = i4; }
  else if (i4 <  9437184) { s = Wq; d = wqb; off = i4 - 8388608; }
  else if (i4 < 10485760) { s = Wk; d = wkb; off = i4 - 9437184; }
  else if (i4 < 11534336) { s = Wv; d = wvb; off = i4 - 10485760; }
  else                    { s = Wp; d = wpb; off = i4 - 11534336; }
  f32x4 v = *(const f32x4*)(s + off);
  bf16x4 bv;
#pragma unroll
  for (int j = 0; j < 4; ++j) bv[j] = (bf16_t)v[j];
  *(bf16x4*)(d + off) = bv;
}

// ---- async GEMM mainloop: acc = A(128 rows) @ W(128 rows)^T over K=1024.
//      Double-buffered global_load_lds, 1 barrier/step, chunk-XOR swizzle:
//      row r chunk c (16B) stored at linear r*32 + (c ^ ((r>>1)&3))*8. ----
__device__ __forceinline__ void gemm_core(
    const bf16_t* __restrict__ A, const bf16_t* __restrict__ W,
    bf16_t (*As)[4096], bf16_t (*Bs)[4096], f32x4 acc[4][4], int m0, int n0)
{
  const int tid = threadIdx.x;
  const int lane = tid & 63, w = tid >> 6;
  const int wm = w >> 1, wn = w & 1;
  const int l15 = lane & 15, quad = lane >> 4;

  // Stage source (pre-swizzled): wave w call i covers rows w*32+i*16+(lane>>2),
  // stored chunk lane&3 must hold source chunk (lane&3)^((lane>>3)&3).
  const int srow = lane >> 2;
  const int schk = (lane & 3) ^ ((lane >> 3) & 3);
  const bf16_t* Ag = A + (size_t)(m0 + w * 32 + srow) * C_EMB + schk * 8;
  const bf16_t* Wg = W + (size_t)(n0 + w * 32 + srow) * C_EMB + schk * 8;

  // prologue: stage k-step 0 into buffer 0
  ldsload16(Ag,              &As[0][w * 1024]);
  ldsload16(Ag + 16 * C_EMB, &As[0][w * 1024 + 512]);
  ldsload16(Wg,              &Bs[0][w * 1024]);
  ldsload16(Wg + 16 * C_EMB, &Bs[0][w * 1024 + 512]);

  for (int ks = 0; ks < 32; ++ks) {
    const int cur = ks & 1;
    // __syncthreads drains vmcnt(0): step ks resident; buf[cur^1] free.
    __syncthreads();
    if (ks < 31) {
      const int nb = cur ^ 1;
      const bf16_t* a2 = Ag + (ks + 1) * 32;
      const bf16_t* w2 = Wg + (ks + 1) * 32;
      ldsload16(a2,              &As[nb][w * 1024]);
      ldsload16(a2 + 16 * C_EMB, &As[nb][w * 1024 + 512]);
      ldsload16(w2,              &Bs[nb][w * 1024]);
      ldsload16(w2 + 16 * C_EMB, &Bs[nb][w * 1024 + 512]);
    }
    bf16x8 af[4], bfr[4];
#pragma unroll
    for (int i = 0; i < 4; ++i) {
      int ra = wm * 64 + i * 16 + l15;
      int ca = quad ^ ((ra >> 1) & 3);
      af[i] = *(const bf16x8*)&As[cur][ra * 32 + ca * 8];
    }
#pragma unroll
    for (int j = 0; j < 4; ++j) {
      int rb = wn * 64 + j * 16 + l15;
      int cb = quad ^ ((rb >> 1) & 3);
      bfr[j] = *(const bf16x8*)&Bs[cur][rb * 32 + cb * 8];
    }
    __builtin_amdgcn_s_setprio(1);
#pragma unroll
    for (int i = 0; i < 4; ++i)
#pragma unroll
      for (int j = 0; j < 4; ++j) acc[i][j] = mfma16(af[i], bfr[j], acc[i][j]);
    __builtin_amdgcn_s_setprio(0);
  }
}

// XCD-contiguous tile remap for grid (8, 64, z): linear id ≡ bx (mod 8) picks
// the XCD, so XCD bx owns m-tiles [bx*8, bx*8+8) x all 8 n-tiles: each A panel
// is HBM-fetched once per XCD; the 2MB W stays L2-resident.
__device__ __forceinline__ void xcd_tiles(int& m0, int& n0) {
  m0 = (blockIdx.x * 8 + (blockIdx.y >> 3)) * 128;
  n0 = (blockIdx.y & 7) * 128;
}

// ---- QKV gemm over all batches (M=8192). z=0 q, z=1 k: RMSNorm+RoPE fused
//      in the epilogue (tile cols = whole 64-dim head groups; rope pair
//      d<->d+32 is j<->j+2 lane-local; RMS = 4 sq + shfl over l15).
//      q additionally scaled by log2(e)/8 (base-2 softmax upstream fold).
//      z=2 v written TRANSPOSED: vt[b][col][t] (bf16x4 along t, no LDS) ----
__global__ __launch_bounds__(256) void gemm_qkv(
    const bf16_t* __restrict__ A,
    const bf16_t* __restrict__ Wqb, const bf16_t* __restrict__ Wkb, const bf16_t* __restrict__ Wvb,
    bf16_t* __restrict__ qo, bf16_t* __restrict__ ko, bf16_t* __restrict__ vt)
{
  const int z = blockIdx.z;
  const bf16_t* W = (z == 0) ? Wqb : ((z == 1) ? Wkb : Wvb);
  int m0, n0; xcd_tiles(m0, n0);
  __shared__ bf16_t As[2][4096];
  __shared__ bf16_t Bs[2][4096];
  const int lane = threadIdx.x & 63, w = threadIdx.x >> 6;
  const int wm = w >> 1, wn = w & 1;
  const int l15 = lane & 15, quad = lane >> 4;
  const f32x4 fz = {0.f, 0.f, 0.f, 0.f};
  f32x4 acc[4][4];
#pragma unroll
  for (int i = 0; i < 4; ++i)
#pragma unroll
    for (int j = 0; j < 4; ++j) acc[i][j] = fz;
  gemm_core(A, W, As, Bs, acc, m0, n0);

  if (z < 2) {
    bf16_t* C = z ? ko : qo;
    const float scale = z ? 1.0f : QSCL2;        // q gets log2(e)/sqrt(64)
#pragma unroll
    for (int i = 0; i < 4; ++i)
#pragma unroll
      for (int r = 0; r < 4; ++r) {
        float v0 = acc[i][0][r], v1 = acc[i][1][r];
        float v2 = acc[i][2][r], v3 = acc[i][3][r];
        float ss = v0 * v0 + v1 * v1 + v2 * v2 + v3 * v3;
#pragma unroll
        for (int mm = 1; mm <= 8; mm <<= 1) ss += __shfl_xor(ss, mm);
        const float rn = rsqrtf(fmaxf(ss, 0.f) * (1.0f / 64.0f) + RMS_EPS);
        const int row = m0 + wm * 64 + i * 16 + quad * 4 + r;
        const float t = (float)(row & (T_SEQ - 1));
        const float n0v = v0 * rn, n1v = v1 * rn, n2v = v2 * rn, n3v = v3 * rn;
        float c0, s0, c1, s1;
        __sincosf(t * __expf(-(float)l15 * 0.28782313662425575f), &s0, &c0);
        __sincosf(t * __expf(-(float)(16 + l15) * 0.28782313662425575f), &s1, &c1);
        const float o0 = (n0v * c0 + n2v * s0) * scale;   // d = l15
        const float o1 = (n1v * c1 + n3v * s1) * scale;   // d = 16+l15
        const float o2 = (n2v * c0 - n0v * s0) * scale;   // d = 32+l15
        const float o3 = (n3v * c1 - n1v * s1) * scale;   // d = 48+l15
        const size_t base = (size_t)row * C_EMB + n0 + wn * 64 + l15;
        C[base]      = (bf16_t)declamp(o0, 1e4f);
        C[base + 16] = (bf16_t)declamp(o1, 1e4f);
        C[base + 32] = (bf16_t)declamp(o2, 1e4f);
        C[base + 48] = (bf16_t)declamp(o3, 1e4f);
      }
  } else {
#pragma unroll
    for (int i = 0; i < 4; ++i)
#pragma unroll
      for (int j = 0; j < 4; ++j) {
        int row = m0 + wm * 64 + i * 16 + quad * 4;   // multiple of 4, same batch
        int col = n0 + wn * 64 + j * 16 + l15;
        bf16x4 pv;
#pragma unroll
        for (int r = 0; r < 4; ++r) pv[r] = (bf16_t)declamp(acc[i][j][r], 1e4f);
        size_t idx = (size_t)(row >> 11) * 2097152 + (size_t)col * 2048 + (row & 2047);
        *(bf16x4*)&vt[idx] = pv;
      }
  }
}

// ---- proj gemm: bf16 A/W -> f32 out ----
__global__ __launch_bounds__(256) void gemm_proj(
    const bf16_t* __restrict__ A, const bf16_t* __restrict__ Wpb, float* __restrict__ C)
{
  int m0, n0; xcd_tiles(m0, n0);
  __shared__ bf16_t As[2][4096];
  __shared__ bf16_t Bs[2][4096];
  const int lane = threadIdx.x & 63, w = threadIdx.x >> 6;
  const int wm = w >> 1, wn = w & 1;
  const int l15 = lane & 15, quad = lane >> 4;
  const f32x4 fz = {0.f, 0.f, 0.f, 0.f};
  f32x4 acc[4][4];
#pragma unroll
  for (int i = 0; i < 4; ++i)
#pragma unroll
    for (int j = 0; j < 4; ++j) acc[i][j] = fz;
  gemm_core(A, Wpb, As, Bs, acc, m0, n0);
#pragma unroll
  for (int i = 0; i < 4; ++i)
#pragma unroll
    for (int j = 0; j < 4; ++j)
#pragma unroll
      for (int r = 0; r < 4; ++r) {
        int row = m0 + wm * 64 + i * 16 + quad * 4 + r;
        int col = n0 + wn * 64 + j * 16 + l15;
        C[(size_t)row * C_EMB + col] = declamp(acc[i][j][r], 1e4f);
      }
}

// ---- FIXED-MAX QK^T + base-2 softmax for one component. K/P tiles pitch 64,
//      XOR chunk swizzle: (row, col=c*8+j) at row*64 + ((c ^ (row&7))*8 + j).
//      Writes P to wave-private pw, then reads back PV A-fragments (pa). ----
__device__ __forceinline__ void qk_sm_fm(
    const bf16_t* __restrict__ ks, bf16_t* __restrict__ pw,
    const bf16x8* qf, float* rsum, bf16x8* pa,
    bool diag, int k0, int q0, int w, int l15, int quad)
{
  const int xs = l15 & 7;        // row&7 for rows ≡ l15 (mod 16)
  f32x4 sc[4];
#pragma unroll
  for (int nt = 0; nt < 4; ++nt) {
    f32x4 a = {0.f, 0.f, 0.f, 0.f};
#pragma unroll
    for (int s = 0; s < 2; ++s) {
      bf16x8 b = *(const bf16x8*)&ks[(nt * 16 + l15) * 64 + ((((s << 2) + quad) ^ xs) << 3)];
      a = mfma16(qf[s], b, a);
    }
#pragma unroll
    for (int r = 0; r < 4; ++r) a[r] = declamp(a[r], 30.f);   // NaN firewall
    sc[nt] = a;
  }
  if (diag) {
#pragma unroll
    for (int nt = 0; nt < 4; ++nt)
#pragma unroll
      for (int r = 0; r < 4; ++r) {
        int col = k0 + nt * 16 + l15;
        int row = q0 + w * 16 + quad * 4 + r;
        if (col > row) sc[nt][r] = -1e30f;
      }
  }
  // P = exp2(S' - M_FIX2) = exp(S - 9); per-lane row partial sums
#pragma unroll
  for (int nt = 0; nt < 4; ++nt)
#pragma unroll
    for (int r = 0; r < 4; ++r) {
      float pv = exp2f(sc[nt][r] - M_FIX2);
      rsum[r] += pv;
      int row = quad * 4 + r;
      int col = nt * 16 + l15;
      pw[row * 64 + ((((col >> 3) ^ (row & 7)) << 3) | (col & 7))] = (bf16_t)pv;
    }
  // read back PV A-fragments (wave-private buffer: no barrier, lgkm only)
#pragma unroll
  for (int s = 0; s < 2; ++s)
    pa[s] = *(const bf16x8*)&pw[l15 * 64 + ((((s << 2) + quad) ^ xs) << 3)];
}

// ---- batch-merged diff attention; K1/K2/V async double-buffered via
//      global_load_lds. LDS = 73728B -> 2 blocks/CU. One barrier per k-tile.
//      FUSED PV: both components' P computed first, one V read feeds both. ----
__global__ __launch_bounds__(256) void diff_attn2(
    const bf16_t* __restrict__ qp, const bf16_t* __restrict__ kp, const bf16_t* __restrict__ vtp,
    const float* __restrict__ lq1, const float* __restrict__ lk1,
    const float* __restrict__ lq2, const float* __restrict__ lk2,
    bf16_t* __restrict__ outp)
{
  // XCD-local remap: linear id ≡ bh (mod 32) -> all 32 q-blocks of one (b,h)
  // share an XCD (id%8), keeping its ~1MB K/V set in that XCD's L2.
  const int bh = blockIdx.x;
  const int bx = 31 - blockIdx.y;          // longest chains dispatched first
  const int b = bh >> 3, h = bh & 7;
  const int q0 = bx * 64;
  const int tid = threadIdx.x;
  const int lane = tid & 63, w = tid >> 6;
  const int l15 = lane & 15, quad = lane >> 4;
  const size_t bT = (size_t)b * T_SEQ;
  const bf16_t* vth = vtp + (size_t)b * 2097152 + (size_t)(h * 128) * 2048;

  __shared__ bf16_t k1s[2][64 * 64];       // all double-buffered, pitch 64,
  __shared__ bf16_t k2s[2][64 * 64];       // XOR chunk swizzle
  __shared__ bf16_t vts[2][128 * 64];
  __shared__ bf16_t ps[4][16 * 64];        // wave-private P scratch

  float e1 = lq1[lane] * lk1[lane];
  float e2 = lq2[lane] * lk2[lane];
#pragma unroll
  for (int mm = 1; mm <= 32; mm <<= 1) { e1 += __shfl_xor(e1, mm); e2 += __shfl_xor(e2, mm); }
  const float lam = expf(declamp(e1, 30.f)) - expf(declamp(e2, 30.f)) + LAMBDA_INIT;

  const int sh1 = 2 * h, sh2 = 2 * h + 1;

  // Staging: per-lane PRE-SWIZZLED global source, linear LDS dest (lane*16B).
  // For any tile with 128B rows: LDS byte o = base + i*1024 + lane*16 ->
  // row r = rbase + i*8 + (lane>>3), chunk c = lane&7; r&7 = lane>>3, so
  // swizzled source chunk = (lane&7) ^ (lane>>3) for K AND V alike.
  const int lrow = lane >> 3;
  const int lchk = (lane & 7) ^ lrow;
  const bf16_t* k1g = kp + (bT + (size_t)(w * 16 + lrow)) * 1024 + sh1 * 64 + (lchk << 3);
  const bf16_t* k2g = kp + (bT + (size_t)(w * 16 + lrow)) * 1024 + sh2 * 64 + (lchk << 3);
  const bf16_t* vg  = vth + (size_t)(w * 32 + lrow) * 2048 + (lchk << 3);

  // prologue: stage tile 0 into buffer 0 (async; drained by first barrier)
  ldsload16(k1g,         &k1s[0][w * 1024]);
  ldsload16(k1g + 8192,  &k1s[0][w * 1024 + 512]);
  ldsload16(k2g,         &k2s[0][w * 1024]);
  ldsload16(k2g + 8192,  &k2s[0][w * 1024 + 512]);
  ldsload16(vg,          &vts[0][w * 2048]);
  ldsload16(vg + 16384,  &vts[0][w * 2048 + 512]);
  ldsload16(vg + 32768,  &vts[0][w * 2048 + 1024]);
  ldsload16(vg + 49152,  &vts[0][w * 2048 + 1536]);

  const int tq = q0 + w * 16 + l15;
  const bf16_t* qrow = qp + (bT + tq) * 1024;
  bf16x8 q1f[2], q2f[2];
#pragma unroll
  for (int s = 0; s < 2; ++s) {
    q1f[s] = *(const bf16x8*)&qrow[sh1 * 64 + s * 32 + quad * 8];
    q2f[s] = *(const bf16x8*)&qrow[sh2 * 64 + s * 32 + quad * 8];
  }

  const f32x4 fz = {0.f, 0.f, 0.f, 0.f};
  f32x4 o1[8], o2[8];
  float rs1[4] = {0, 0, 0, 0}, rs2[4] = {0, 0, 0, 0};
#pragma unroll
  for (int i = 0; i < 8; ++i) { o1[i] = fz; o2[i] = fz; }

  const int xs = l15 & 7;

  for (int kt = 0; kt <= bx; ++kt) {
    const int cur = kt & 1;
    // __syncthreads drains vmcnt(0): tile kt (issued last iter / prologue) is
    // resident for ALL waves, and all waves finished reading buf[cur^1].
    __syncthreads();
    if (kt < bx) {                         // issue next tile into the freed buffer
      const int nb = cur ^ 1;
      const bf16_t* s1 = k1g + (size_t)(kt + 1) * 65536;
      const bf16_t* s2 = k2g + (size_t)(kt + 1) * 65536;
      const bf16_t* sv = vg + (size_t)(kt + 1) * 64;
      ldsload16(s1,         &k1s[nb][w * 1024]);
      ldsload16(s1 + 8192,  &k1s[nb][w * 1024 + 512]);
      ldsload16(s2,         &k2s[nb][w * 1024]);
      ldsload16(s2 + 8192,  &k2s[nb][w * 1024 + 512]);
      ldsload16(sv,         &vts[nb][w * 2048]);
      ldsload16(sv + 16384, &vts[nb][w * 2048 + 512]);
      ldsload16(sv + 32768, &vts[nb][w * 2048 + 1024]);
      ldsload16(sv + 49152, &vts[nb][w * 2048 + 1536]);
    }
    const int k0 = kt * 64;
    const bool diag = (kt == bx);

    bf16x8 pa1[2], pa2[2];
    qk_sm_fm(&k1s[cur][0], ps[w], q1f, rs1, pa1, diag, k0, q0, w, l15, quad);
    qk_sm_fm(&k2s[cur][0], ps[w], q2f, rs2, pa2, diag, k0, q0, w, l15, quad);

    // O += P(16x64) @ V(64x128), both components off one V read
    __builtin_amdgcn_s_setprio(1);
#pragma unroll
    for (int s = 0; s < 2; ++s) {
#pragma unroll
      for (int nt2 = 0; nt2 < 8; ++nt2) {
        bf16x8 vb = *(const bf16x8*)&vts[cur][(nt2 * 16 + l15) * 64 + ((((s << 2) + quad) ^ xs) << 3)];
        o1[nt2] = mfma16(pa1[s], vb, o1[nt2]);
        o2[nt2] = mfma16(pa2[s], vb, o2[nt2]);
      }
    }
    __builtin_amdgcn_s_setprio(0);
  }

  // epilogue: single shuffle-reduce of row sums, then diff + LN + store
#pragma unroll
  for (int mm = 1; mm <= 8; mm <<= 1)
#pragma unroll
    for (int r = 0; r < 4; ++r) { rs1[r] += __shfl_xor(rs1[r], mm); rs2[r] += __shfl_xor(rs2[r], mm); }
  float i1[4], i2[4];
#pragma unroll
  for (int r = 0; r < 4; ++r) { i1[r] = 1.f / rs1[r]; i2[r] = 1.f / rs2[r]; }
  f32x4 od[8];
  float sum[4] = {0, 0, 0, 0}, sq[4] = {0, 0, 0, 0};
#pragma unroll
  for (int nt2 = 0; nt2 < 8; ++nt2)
#pragma unroll
    for (int r = 0; r < 4; ++r) {
      float v = declamp(o1[nt2][r] * i1[r] - lam * o2[nt2][r] * i2[r], 1e4f);
      od[nt2][r] = v;
      sum[r] += v;
      sq[r] += v * v;
    }
#pragma unroll
  for (int mm = 1; mm <= 8; mm <<= 1)
#pragma unroll
    for (int r = 0; r < 4; ++r) { sum[r] += __shfl_xor(sum[r], mm); sq[r] += __shfl_xor(sq[r], mm); }
  float mu[4], scl[4];
#pragma unroll
  for (int r = 0; r < 4; ++r) {
    mu[r] = sum[r] * (1.0f / 128.0f);
    float var = sq[r] * (1.0f / 128.0f) - mu[r] * mu[r];
    scl[r] = rsqrtf(fmaxf(var, 0.f) + LN_EPS) * ONE_MINUS_LI;
  }
#pragma unroll
  for (int nt2 = 0; nt2 < 8; ++nt2)
#pragma unroll
    for (int r = 0; r < 4; ++r) {
      int trow = q0 + w * 16 + quad * 4 + r;
      outp[(bT + trow) * 1024 + h * 128 + nt2 * 16 + l15] =
          (bf16_t)((od[nt2][r] - mu[r]) * scl[r]);
    }
}

// ==================== FALLBACK PATH (round-4, zero ws) ====================

__device__ __forceinline__ void attn_step(
    const bf16_t* __restrict__ ks, bf16_t* __restrict__ pw, const bf16_t* __restrict__ vts,
    const bf16x8* qf, float* mR, float* lR, f32x4* o,
    bool diag, int k0, int q0, int w, int l15, int quad)
{
  f32x4 sc[4];
#pragma unroll
  for (int nt = 0; nt < 4; ++nt) {
    f32x4 a = {0.f, 0.f, 0.f, 0.f};
#pragma unroll
    for (int s = 0; s < 2; ++s) {
      bf16x8 b = *(const bf16x8*)&ks[(nt * 16 + l15) * 72 + s * 32 + quad * 8];
      a = mfma16(qf[s], b, a);
    }
#pragma unroll
    for (int r = 0; r < 4; ++r) a[r] = declamp(a[r], 1e4f);
    sc[nt] = a;
  }
  if (diag) {
#pragma unroll
    for (int nt = 0; nt < 4; ++nt)
#pragma unroll
      for (int r = 0; r < 4; ++r) {
        int col = k0 + nt * 16 + l15;
        int row = q0 + w * 16 + quad * 4 + r;
        if (col > row) sc[nt][r] = -1e30f;
      }
  }
  float mx[4];
#pragma unroll
  for (int r = 0; r < 4; ++r)
    mx[r] = fmaxf(fmaxf(sc[0][r], sc[1][r]), fmaxf(sc[2][r], sc[3][r]));
#pragma unroll
  for (int mm = 1; mm <= 8; mm <<= 1)
#pragma unroll
    for (int r = 0; r < 4; ++r) mx[r] = fmaxf(mx[r], __shfl_xor(mx[r], mm));

  float mnew[4], alpha[4], rs[4];
#pragma unroll
  for (int r = 0; r < 4; ++r) {
    mnew[r] = fmaxf(mR[r], mx[r]);
    alpha[r] = __expf(mR[r] - mnew[r]);
    rs[r] = 0.f;
  }
#pragma unroll
  for (int nt = 0; nt < 4; ++nt)
#pragma unroll
    for (int r = 0; r < 4; ++r) {
      float pv = __expf(sc[nt][r] - mnew[r]);
      rs[r] += pv;
      pw[(quad * 4 + r) * 72 + nt * 16 + l15] = (bf16_t)pv;
    }
#pragma unroll
  for (int mm = 1; mm <= 8; mm <<= 1)
#pragma unroll
    for (int r = 0; r < 4; ++r) rs[r] += __shfl_xor(rs[r], mm);
#pragma unroll
  for (int r = 0; r < 4; ++r) {
    lR[r] = lR[r] * alpha[r] + rs[r];
    mR[r] = mnew[r];
  }
#pragma unroll
  for (int nt2 = 0; nt2 < 8; ++nt2)
#pragma unroll
    for (int r = 0; r < 4; ++r) o[nt2][r] *= alpha[r];
#pragma unroll
  for (int s = 0; s < 2; ++s) {
    bf16x8 pa = *(const bf16x8*)&pw[l15 * 72 + s * 32 + quad * 8];
#pragma unroll
    for (int nt2 = 0; nt2 < 8; ++nt2) {
      bf16x8 vb = *(const bf16x8*)&vts[(nt2 * 16 + l15) * 72 + s * 32 + quad * 8];
      o[nt2] = mfma16(pa, vb, o[nt2]);
    }
  }
}

template<bool A_F32, bool OUT_F32>
__global__ __launch_bounds__(256) void gemm_bt(
    const void* __restrict__ Ap,
    const float* __restrict__ W0, const float* __restrict__ W1, const float* __restrict__ W2,
    void* __restrict__ Cp0, void* __restrict__ Cp1, void* __restrict__ Cp2)
{
  const float* W = (blockIdx.z == 0) ? W0 : ((blockIdx.z == 1) ? W1 : W2);
  void*       Cv = (blockIdx.z == 0) ? Cp0 : ((blockIdx.z == 1) ? Cp1 : Cp2);
  const int K = C_EMB, N = C_EMB;
  const int n0 = blockIdx.x * 128, m0 = blockIdx.y * 128;
  __shared__ bf16_t As[128 * 40];
  __shared__ bf16_t Bs[128 * 40];
  const int tid = threadIdx.x;
  const int lane = tid & 63, w = tid >> 6;
  const int wm = w >> 1, wn = w & 1;
  const int l15 = lane & 15, quad = lane >> 4;
  const f32x4 fz = {0.f, 0.f, 0.f, 0.f};
  f32x4 acc[4][4];
#pragma unroll
  for (int i = 0; i < 4; ++i)
#pragma unroll
    for (int j = 0; j < 4; ++j) acc[i][j] = fz;

  for (int k0 = 0; k0 < K; k0 += 32) {
    if constexpr (A_F32) {
      const float* Af = (const float*)Ap;
#pragma unroll
      for (int i = 0; i < 4; ++i) {
        int c = tid + i * 256;
        int r = c >> 3, c4 = (c & 7) * 4;
        f32x4 v = *(const f32x4*)&Af[(size_t)(m0 + r) * K + k0 + c4];
        bf16x4 bv;
#pragma unroll
        for (int j = 0; j < 4; ++j) bv[j] = (bf16_t)v[j];
        *(bf16x4*)&As[r * 40 + c4] = bv;
      }
    } else {
      const bf16_t* Ab = (const bf16_t*)Ap;
#pragma unroll
      for (int i = 0; i < 2; ++i) {
        int c = tid + i * 256;
        int r = c >> 2, c8 = (c & 3) * 8;
        *(bf16x8*)&As[r * 40 + c8] = *(const bf16x8*)&Ab[(size_t)(m0 + r) * K + k0 + c8];
      }
    }
#pragma unroll
    for (int i = 0; i < 4; ++i) {
      int c = tid + i * 256;
      int r = c >> 3, c4 = (c & 7) * 4;
      f32x4 v = *(const f32x4*)&W[(size_t)(n0 + r) * K + k0 + c4];
      bf16x4 bv;
#pragma unroll
      for (int j = 0; j < 4; ++j) bv[j] = (bf16_t)v[j];
      *(bf16x4*)&Bs[r * 40 + c4] = bv;
    }
    __syncthreads();
    bf16x8 af[4], bfr[4];
#pragma unroll
    for (int i = 0; i < 4; ++i)
      af[i] = *(const bf16x8*)&As[(wm * 64 + i * 16 + l15) * 40 + quad * 8];
#pragma unroll
    for (int j = 0; j < 4; ++j)
      bfr[j] = *(const bf16x8*)&Bs[(wn * 64 + j * 16 + l15) * 40 + quad * 8];
#pragma unroll
    for (int i = 0; i < 4; ++i)
#pragma unroll
      for (int j = 0; j < 4; ++j) acc[i][j] = mfma16(af[i], bfr[j], acc[i][j]);
    __syncthreads();
  }
#pragma unroll
  for (int i = 0; i < 4; ++i)
#pragma unroll
    for (int j = 0; j < 4; ++j)
#pragma unroll
      for (int r = 0; r < 4; ++r) {
        int row = m0 + wm * 64 + i * 16 + quad * 4 + r;
        int col = n0 + wn * 64 + j * 16 + l15;
        float v = declamp(acc[i][j][r], 1e4f);
        if constexpr (OUT_F32) ((float*)Cv)[(size_t)row * N + col] = v;
        else                   ((bf16_t*)Cv)[(size_t)row * N + col] = (bf16_t)v;
      }
}

__global__ __launch_bounds__(256) void rope_rms(bf16_t* __restrict__ arr, int is_q)
{
  const int tid = threadIdx.x;
  const int g = blockIdx.x * 16 + (tid >> 4);
  const int l16 = tid & 15;
  const int t = (g >> 4) & (T_SEQ - 1);
  bf16_t* p = arr + (size_t)g * 64 + l16 * 4;
  bf16x4 xv = *(const bf16x4*)p;
  float x[4];
#pragma unroll
  for (int j = 0; j < 4; ++j) x[j] = (float)xv[j];
  float ss = x[0]*x[0] + x[1]*x[1] + x[2]*x[2] + x[3]*x[3];
#pragma unroll
  for (int mm = 1; mm <= 8; mm <<= 1) ss += __shfl_xor(ss, mm);
  const float rn = rsqrtf(fmaxf(ss, 0.f) * (1.0f / 64.0f) + RMS_EPS);
  float nrm[4], prt[4];
#pragma unroll
  for (int j = 0; j < 4; ++j) nrm[j] = x[j] * rn;
#pragma unroll
  for (int j = 0; j < 4; ++j) prt[j] = __shfl_xor(nrm[j], 8);
  const int ib = (l16 & 7) * 4;
  const float sgn = (l16 < 8) ? 1.f : -1.f;
  const float scale = is_q ? 0.125f : 1.0f;
  bf16x4 ov;
#pragma unroll
  for (int j = 0; j < 4; ++j) {
    int i = ib + j;
    float invf = __expf(-(float)i * 0.28782313662425575f);
    float ang = (float)t * invf;
    float c, s;
    __sincosf(ang, &s, &c);
    ov[j] = (bf16_t)((nrm[j] * c + sgn * prt[j] * s) * scale);
  }
  *(bf16x4*)p = ov;
}

__global__ __launch_bounds__(256) void diff_attn(
    const bf16_t* qp, const bf16_t* __restrict__ kp, const bf16_t* __restrict__ vp,
    const float* __restrict__ lq1, const float* __restrict__ lk1,
    const float* __restrict__ lq2, const float* __restrict__ lk2,
    bf16_t* outp)
{
  const int bx = blockIdx.x;
  const int h = blockIdx.y;
  const int q0 = bx * 64;
  const int tid = threadIdx.x;
  const int lane = tid & 63, w = tid >> 6;
  const int l15 = lane & 15, quad = lane >> 4;

  __shared__ bf16_t k1s[64 * 72];
  __shared__ bf16_t k2s[64 * 72];
  __shared__ bf16_t vts[128 * 72];
  __shared__ bf16_t ps[4][16 * 72];

  float e1 = lq1[lane] * lk1[lane];
  float e2 = lq2[lane] * lk2[lane];
#pragma unroll
  for (int mm = 1; mm <= 32; mm <<= 1) { e1 += __shfl_xor(e1, mm); e2 += __shfl_xor(e2, mm); }
  const float lam = expf(declamp(e1, 30.f)) - expf(declamp(e2, 30.f)) + LAMBDA_INIT;

  const int sh1 = 2 * h, sh2 = 2 * h + 1;
  const int tq = q0 + w * 16 + l15;
  const bf16_t* qrow = qp + (size_t)tq * 1024;
  bf16x8 q1f[2], q2f[2];
#pragma unroll
  for (int s = 0; s < 2; ++s) {
    q1f[s] = *(const bf16x8*)&qrow[sh1 * 64 + s * 32 + quad * 8];
    q2f[s] = *(const bf16x8*)&qrow[sh2 * 64 + s * 32 + quad * 8];
  }
  const f32x4 fz = {0.f, 0.f, 0.f, 0.f};
  f32x4 o1[8], o2[8];
  float m1[4], l1[4], m2[4], l2[4];
#pragma unroll
  for (int i = 0; i < 8; ++i) { o1[i] = fz; o2[i] = fz; }
#pragma unroll
  for (int r = 0; r < 4; ++r) { m1[r] = -1e30f; m2[r] = -1e30f; l1[r] = 0.f; l2[r] = 0.f; }

  for (int kt = 0; kt <= bx; ++kt) {
    const int k0 = kt * 64;
    __syncthreads();
#pragma unroll
    for (int i = 0; i < 2; ++i) {
      int c = tid + i * 256;
      int r = c >> 3, c8 = (c & 7) * 8;
      const bf16_t* krow = kp + (size_t)(k0 + r) * 1024;
      *(bf16x8*)&k1s[r * 72 + c8] = *(const bf16x8*)&krow[sh1 * 64 + c8];
      *(bf16x8*)&k2s[r * 72 + c8] = *(const bf16x8*)&krow[sh2 * 64 + c8];
    }
#pragma unroll
    for (int i = 0; i < 4; ++i) {
      int c = tid + i * 256;
      int r = c >> 4, d8 = (c & 15) * 8;
      bf16x8 vv = *(const bf16x8*)&vp[(size_t)(k0 + r) * 1024 + h * 128 + d8];
#pragma unroll
      for (int jj = 0; jj < 8; ++jj) vts[(d8 + jj) * 72 + r] = vv[jj];
    }
    __syncthreads();
    const bool diag = (kt == bx);
    attn_step(k1s, ps[w], vts, q1f, m1, l1, o1, diag, k0, q0, w, l15, quad);
    attn_step(k2s, ps[w], vts, q2f, m2, l2, o2, diag, k0, q0, w, l15, quad);
  }
  float i1[4], i2[4];
#pragma unroll
  for (int r = 0; r < 4; ++r) { i1[r] = 1.f / l1[r]; i2[r] = 1.f / l2[r]; }
  f32x4 od[8];
  float sum[4] = {0, 0, 0, 0}, sq[4] = {0, 0, 0, 0};
#pragma unroll
  for (int nt2 = 0; nt2 < 8; ++nt2)
#pragma unroll
    for (int r = 0; r < 4; ++r) {
      float v = declamp(o1[nt2][r] * i1[r] - lam * o2[nt2][r] * i2[r], 1e4f);
      od[nt2][r] = v;
      sum[r] += v;
      sq[r] += v * v;
    }
#pragma unroll
  for (int mm = 1; mm <= 8; mm <<= 1)
#pragma unroll
    for (int r = 0; r < 4; ++r) { sum[r] += __shfl_xor(sum[r], mm); sq[r] += __shfl_xor(sq[r], mm); }
  float mu[4], scl[4];
#pragma unroll
  for (int r = 0; r < 4; ++r) {
    mu[r] = sum[r] * (1.0f / 128.0f);
    float var = sq[r] * (1.0f / 128.0f) - mu[r] * mu[r];
    scl[r] = rsqrtf(fmaxf(var, 0.f) + LN_EPS) * ONE_MINUS_LI;
  }
#pragma unroll
  for (int nt2 = 0; nt2 < 8; ++nt2)
#pragma unroll
    for (int r = 0; r < 4; ++r) {
      int trow = q0 + w * 16 + quad * 4 + r;
      outp[(size_t)trow * 1024 + h * 128 + nt2 * 16 + l15] =
          (bf16_t)((od[nt2][r] - mu[r]) * scl[r]);
    }
}

// ==================== launch ====================
extern "C" void kernel_launch(void* const* d_in, const int* in_sizes, int n_in,
                              void* d_out, int out_size, void* d_ws, size_t ws_size,
                              hipStream_t stream) {
  const float* x     = (const float*)d_in[0];
  const float* Wq    = (const float*)d_in[1];
  const float* Wk    = (const float*)d_in[2];
  const float* Wv    = (const float*)d_in[3];
  const float* Wproj = (const float*)d_in[4];
  const float* lq1   = (const float*)d_in[5];
  const float* lk1   = (const float*)d_in[6];
  const float* lq2   = (const float*)d_in[7];
  const float* lk2   = (const float*)d_in[8];
  float* O = (float*)d_out;
  const size_t R = (size_t)T_SEQ * C_EMB;

  if (ws_size >= (size_t)40 * 1024 * 1024) {
    // ---------- FAST PATH ----------
    bf16_t* wsb = (bf16_t*)d_ws;
    bf16_t* xb  = wsb;                       // [0, 8M elems) ; reused as attn-out
    bf16_t* wqb = wsb + 8388608;
    bf16_t* wkb = wqb + 1048576;
    bf16_t* wvb = wkb + 1048576;
    bf16_t* wpb = wvb + 1048576;
    bf16_t* vt  = wpb + 1048576;             // [12M, 20M elems) = 16MB
    bf16_t* qo  = (bf16_t*)d_out;            // d_out low half
    bf16_t* ko  = qo + 8388608;              // d_out high half
    bf16_t* a   = xb;                        // attn-out over dead xb

    cvt_all<<<12288, 256, 0, stream>>>(x, Wq, Wk, Wv, Wproj, xb, wqb, wkb, wvb, wpb);
    gemm_qkv<<<dim3(8, 64, 3), 256, 0, stream>>>(xb, wqb, wkb, wvb, qo, ko, vt);
    diff_attn2<<<dim3(32, 32), 256, 0, stream>>>(qo, ko, vt, lq1, lk1, lq2, lk2, a);
    gemm_proj<<<dim3(8, 64), 256, 0, stream>>>(a, wpb, O);
  } else {
    // ---------- FALLBACK (round-4 proven, zero ws) ----------
    char* Ob = (char*)d_out;
    char* Xb = (char*)d_in[0];
    const size_t MB4 = (size_t)1 << 22;
    bf16_t* qb[4] = { (bf16_t*)(Ob + 2*MB4), (bf16_t*)(Ob + 5*MB4),
                      (bf16_t*)(Xb + 0*MB4), (bf16_t*)(Xb + 3*MB4) };
    bf16_t* kb[4] = { (bf16_t*)(Ob + 3*MB4), (bf16_t*)(Ob + 6*MB4),
                      (bf16_t*)(Xb + 1*MB4), (bf16_t*)(Xb + 4*MB4) };
    bf16_t* vb[4] = { (bf16_t*)(Ob + 4*MB4), (bf16_t*)(Ob + 7*MB4),
                      (bf16_t*)(Xb + 2*MB4), (bf16_t*)(Xb + 5*MB4) };
    for (int b = 0; b < 4; ++b) {
      const float* xbp = x + (size_t)b * R;
      gemm_bt<true, false><<<dim3(8, 16, 3), 256, 0, stream>>>(
          xbp, Wq, Wk, Wv, qb[b], kb[b], vb[b]);
      rope_rms<<<2048, 256, 0, stream>>>(qb[b], 1);
      rope_rms<<<2048, 256, 0, stream>>>(kb[b], 0);
      diff_attn<<<dim3(32, 8), 256, 0, stream>>>(qb[b], kb[b], vb[b],
                                                 lq1, lk1, lq2, lk2, qb[b]);
      gemm_bt<false, true><<<dim3(8, 16, 1), 256, 0, stream>>>(
          qb[b], Wproj, Wproj, Wproj, O + (size_t)b * R, nullptr, nullptr);
    }
  }
}

// Round 9
// 291.265 us; speedup vs baseline: 1.0509x; 1.0509x over previous
//
#include <hip/hip_runtime.h>
#include <hip/hip_bf16.h>
#include <math.h>

// Differential causal self-attention. ALL I/O float32; internal bf16 MFMA.
// FAST PATH (ws_size >= 40MB): batch-merged launches, 4 dispatches.
//   ws: [0,16M) xb (x as bf16; reused as attn-out after QKV consumes it)
//       [16M,24M) Wq,Wk,Wv,Wproj as bf16 (2MB each)
//       [24M,40M) vt = V transposed per batch: vt[b][dim 0..1023][t 0..2047]
//   d_out: [0,16M) q bf16, [16M,32M) k bf16 (dead before proj writes f32)
// Attention: FIXED-max softmax in BASE-2 (q pre-scaled by log2e; P =
//   exp2(S' - 9*log2e) = exp(S-9); rmsnorm bounds |S|<=8.05).
// Round 16: RESUBMIT of round 15 (bench infra failed twice; no data).
//   Round-13 verified attn structure + ONE isolated variable:
//   __builtin_amdgcn_exp2f (bare v_exp_f32) with the log2e fold kept in
//   gemm_qkv's q-scale. Round-14 lesson: OCML exp2f is a multi-inst
//   correctly-rounded path (+24% VALU cycles); the builtin avoids it.
// Round 13 (kept): RMSNorm+RoPE fused in gemm_qkv epilogue; diff_attn2 =
//   async gload_lds dbuf K1/K2/V, 1 barrier/k-tile, grid (32,32), 2 blk/CU.
// Round 10 (kept): GEMMs on async gload_lds dbuf, 1 barrier/step, XCD tiles.
// Round 8 (kept): XCD-local bh=blockIdx.x remap (FETCH 125->38MB).
// Ledger: VGPR must stay <128 (r5: 148 VGPR -> 1 blk/CU); PV fusion
//   regressed when paired with lib exp2f (r14); pair-balancing regressed
//   (r12); LDS not the occupancy binder at 73728 (r11).
// FALLBACK (small ws): round-4 proven per-batch pipeline, zero ws usage.

typedef __bf16 bf16_t;
typedef __bf16 bf16x8 __attribute__((ext_vector_type(8)));
typedef __bf16 bf16x4 __attribute__((ext_vector_type(4)));
typedef float  f32x4  __attribute__((ext_vector_type(4)));

#define T_SEQ 2048
#define C_EMB 1024
static constexpr float LAMBDA_INIT = 0.6192834728526787f;   // 0.8 - 0.6*exp(-1.2)
static constexpr float ONE_MINUS_LI = 0.3807165271473213f;
static constexpr float RMS_EPS = 1.1920928955078125e-07f;
static constexpr float LN_EPS = 1e-5f;
static constexpr float M_FIX2 = 12.984255368000671f;  // 9 * log2(e): fixed max, base-2
static constexpr float QSCL2  = 0.18033688011112042f; // 0.125 * log2(e)

__device__ __forceinline__ f32x4 mfma16(bf16x8 a, bf16x8 b, f32x4 c) {
  return __builtin_amdgcn_mfma_f32_16x16x32_bf16(a, b, c, 0, 0, 0);
}
__device__ __forceinline__ float declamp(float v, float lim) {
  return fminf(fmaxf(v, -lim), lim);   // IEEE min/max: NaN firewall too
}
__device__ __forceinline__ float fexp2(float x) {
  return __builtin_amdgcn_exp2f(x);    // bare v_exp_f32 (no OCML fixup path)
}
// async global->LDS, 16B per lane; lds dest must be wave-uniform base (+lane*16)
__device__ __forceinline__ void ldsload16(const bf16_t* g, bf16_t* l) {
  __builtin_amdgcn_global_load_lds(
      (const __attribute__((address_space(1))) void*)g,
      (__attribute__((address_space(3))) void*)l, 16, 0, 0);
}

// ==================== FAST PATH ====================

// ---- one-shot f32 -> bf16 convert: x (8M) + 4 weights (1M each) ----
__global__ __launch_bounds__(256) void cvt_all(
    const float* __restrict__ x,  const float* __restrict__ Wq,
    const float* __restrict__ Wk, const float* __restrict__ Wv,
    const float* __restrict__ Wp,
    bf16_t* __restrict__ xb,  bf16_t* __restrict__ wqb, bf16_t* __restrict__ wkb,
    bf16_t* __restrict__ wvb, bf16_t* __restrict__ wpb)
{
  size_t i4 = ((size_t)blockIdx.x * 256 + threadIdx.x) * 4;
  const float* s; bf16_t* d; size_t off;
  if      (i4 <  8388608) { s = x;  d = xb;  off = i4; }
  else if (i4 <  9437184) { s = Wq; d = wqb; off = i4 - 8388608; }
  else if (i4 < 10485760) { s = Wk; d = wkb; off = i4 - 9437184; }
  else if (i4 < 11534336) { s = Wv; d = wvb; off = i4 - 10485760; }
  else                    { s = Wp; d = wpb; off = i4 - 11534336; }
  f32x4 v = *(const f32x4*)(s + off);
  bf16x4 bv;
#pragma unroll
  for (int j = 0; j < 4; ++j) bv[j] = (bf16_t)v[j];
  *(bf16x4*)(d + off) = bv;
}

// ---- async GEMM mainloop: acc = A(128 rows) @ W(128 rows)^T over K=1024.
//      Double-buffered global_load_lds, 1 barrier/step, chunk-XOR swizzle:
//      row r chunk c (16B) stored at linear r*32 + (c ^ ((r>>1)&3))*8. ----
__device__ __forceinline__ void gemm_core(
    const bf16_t* __restrict__ A, const bf16_t* __restrict__ W,
    bf16_t (*As)[4096], bf16_t (*Bs)[4096], f32x4 acc[4][4], int m0, int n0)
{
  const int tid = threadIdx.x;
  const int lane = tid & 63, w = tid >> 6;
  const int wm = w >> 1, wn = w & 1;
  const int l15 = lane & 15, quad = lane >> 4;

  // Stage source (pre-swizzled): wave w call i covers rows w*32+i*16+(lane>>2),
  // stored chunk lane&3 must hold source chunk (lane&3)^((lane>>3)&3).
  const int srow = lane >> 2;
  const int schk = (lane & 3) ^ ((lane >> 3) & 3);
  const bf16_t* Ag = A + (size_t)(m0 + w * 32 + srow) * C_EMB + schk * 8;
  const bf16_t* Wg = W + (size_t)(n0 + w * 32 + srow) * C_EMB + schk * 8;

  // prologue: stage k-step 0 into buffer 0
  ldsload16(Ag,              &As[0][w * 1024]);
  ldsload16(Ag + 16 * C_EMB, &As[0][w * 1024 + 512]);
  ldsload16(Wg,              &Bs[0][w * 1024]);
  ldsload16(Wg + 16 * C_EMB, &Bs[0][w * 1024 + 512]);

  for (int ks = 0; ks < 32; ++ks) {
    const int cur = ks & 1;
    // __syncthreads drains vmcnt(0): step ks resident; buf[cur^1] free.
    __syncthreads();
    if (ks < 31) {
      const int nb = cur ^ 1;
      const bf16_t* a2 = Ag + (ks + 1) * 32;
      const bf16_t* w2 = Wg + (ks + 1) * 32;
      ldsload16(a2,              &As[nb][w * 1024]);
      ldsload16(a2 + 16 * C_EMB, &As[nb][w * 1024 + 512]);
      ldsload16(w2,              &Bs[nb][w * 1024]);
      ldsload16(w2 + 16 * C_EMB, &Bs[nb][w * 1024 + 512]);
    }
    bf16x8 af[4], bfr[4];
#pragma unroll
    for (int i = 0; i < 4; ++i) {
      int ra = wm * 64 + i * 16 + l15;
      int ca = quad ^ ((ra >> 1) & 3);
      af[i] = *(const bf16x8*)&As[cur][ra * 32 + ca * 8];
    }
#pragma unroll
    for (int j = 0; j < 4; ++j) {
      int rb = wn * 64 + j * 16 + l15;
      int cb = quad ^ ((rb >> 1) & 3);
      bfr[j] = *(const bf16x8*)&Bs[cur][rb * 32 + cb * 8];
    }
    __builtin_amdgcn_s_setprio(1);
#pragma unroll
    for (int i = 0; i < 4; ++i)
#pragma unroll
      for (int j = 0; j < 4; ++j) acc[i][j] = mfma16(af[i], bfr[j], acc[i][j]);
    __builtin_amdgcn_s_setprio(0);
  }
}

// XCD-contiguous tile remap for grid (8, 64, z): linear id ≡ bx (mod 8) picks
// the XCD, so XCD bx owns m-tiles [bx*8, bx*8+8) x all 8 n-tiles: each A panel
// is HBM-fetched once per XCD; the 2MB W stays L2-resident.
__device__ __forceinline__ void xcd_tiles(int& m0, int& n0) {
  m0 = (blockIdx.x * 8 + (blockIdx.y >> 3)) * 128;
  n0 = (blockIdx.y & 7) * 128;
}

// ---- QKV gemm over all batches (M=8192). z=0 q, z=1 k: RMSNorm+RoPE fused
//      in the epilogue (tile cols = whole 64-dim head groups; rope pair
//      d<->d+32 is j<->j+2 lane-local; RMS = 4 sq + shfl over l15).
//      q additionally scaled by log2(e)/8 (base-2 softmax upstream fold).
//      z=2 v written TRANSPOSED: vt[b][col][t] (bf16x4 along t, no LDS) ----
__global__ __launch_bounds__(256) void gemm_qkv(
    const bf16_t* __restrict__ A,
    const bf16_t* __restrict__ Wqb, const bf16_t* __restrict__ Wkb, const bf16_t* __restrict__ Wvb,
    bf16_t* __restrict__ qo, bf16_t* __restrict__ ko, bf16_t* __restrict__ vt)
{
  const int z = blockIdx.z;
  const bf16_t* W = (z == 0) ? Wqb : ((z == 1) ? Wkb : Wvb);
  int m0, n0; xcd_tiles(m0, n0);
  __shared__ bf16_t As[2][4096];
  __shared__ bf16_t Bs[2][4096];
  const int lane = threadIdx.x & 63, w = threadIdx.x >> 6;
  const int wm = w >> 1, wn = w & 1;
  const int l15 = lane & 15, quad = lane >> 4;
  const f32x4 fz = {0.f, 0.f, 0.f, 0.f};
  f32x4 acc[4][4];
#pragma unroll
  for (int i = 0; i < 4; ++i)
#pragma unroll
    for (int j = 0; j < 4; ++j) acc[i][j] = fz;
  gemm_core(A, W, As, Bs, acc, m0, n0);

  if (z < 2) {
    bf16_t* C = z ? ko : qo;
    const float scale = z ? 1.0f : QSCL2;        // q gets log2(e)/sqrt(64)
#pragma unroll
    for (int i = 0; i < 4; ++i)
#pragma unroll
      for (int r = 0; r < 4; ++r) {
        float v0 = acc[i][0][r], v1 = acc[i][1][r];
        float v2 = acc[i][2][r], v3 = acc[i][3][r];
        float ss = v0 * v0 + v1 * v1 + v2 * v2 + v3 * v3;
#pragma unroll
        for (int mm = 1; mm <= 8; mm <<= 1) ss += __shfl_xor(ss, mm);
        const float rn = rsqrtf(fmaxf(ss, 0.f) * (1.0f / 64.0f) + RMS_EPS);
        const int row = m0 + wm * 64 + i * 16 + quad * 4 + r;
        const float t = (float)(row & (T_SEQ - 1));
        const float n0v = v0 * rn, n1v = v1 * rn, n2v = v2 * rn, n3v = v3 * rn;
        float c0, s0, c1, s1;
        __sincosf(t * __expf(-(float)l15 * 0.28782313662425575f), &s0, &c0);
        __sincosf(t * __expf(-(float)(16 + l15) * 0.28782313662425575f), &s1, &c1);
        const float o0 = (n0v * c0 + n2v * s0) * scale;   // d = l15
        const float o1 = (n1v * c1 + n3v * s1) * scale;   // d = 16+l15
        const float o2 = (n2v * c0 - n0v * s0) * scale;   // d = 32+l15
        const float o3 = (n3v * c1 - n1v * s1) * scale;   // d = 48+l15
        const size_t base = (size_t)row * C_EMB + n0 + wn * 64 + l15;
        C[base]      = (bf16_t)declamp(o0, 1e4f);
        C[base + 16] = (bf16_t)declamp(o1, 1e4f);
        C[base + 32] = (bf16_t)declamp(o2, 1e4f);
        C[base + 48] = (bf16_t)declamp(o3, 1e4f);
      }
  } else {
#pragma unroll
    for (int i = 0; i < 4; ++i)
#pragma unroll
      for (int j = 0; j < 4; ++j) {
        int row = m0 + wm * 64 + i * 16 + quad * 4;   // multiple of 4, same batch
        int col = n0 + wn * 64 + j * 16 + l15;
        bf16x4 pv;
#pragma unroll
        for (int r = 0; r < 4; ++r) pv[r] = (bf16_t)declamp(acc[i][j][r], 1e4f);
        size_t idx = (size_t)(row >> 11) * 2097152 + (size_t)col * 2048 + (row & 2047);
        *(bf16x4*)&vt[idx] = pv;
      }
  }
}

// ---- proj gemm: bf16 A/W -> f32 out ----
__global__ __launch_bounds__(256) void gemm_proj(
    const bf16_t* __restrict__ A, const bf16_t* __restrict__ Wpb, float* __restrict__ C)
{
  int m0, n0; xcd_tiles(m0, n0);
  __shared__ bf16_t As[2][4096];
  __shared__ bf16_t Bs[2][4096];
  const int lane = threadIdx.x & 63, w = threadIdx.x >> 6;
  const int wm = w >> 1, wn = w & 1;
  const int l15 = lane & 15, quad = lane >> 4;
  const f32x4 fz = {0.f, 0.f, 0.f, 0.f};
  f32x4 acc[4][4];
#pragma unroll
  for (int i = 0; i < 4; ++i)
#pragma unroll
    for (int j = 0; j < 4; ++j) acc[i][j] = fz;
  gemm_core(A, Wpb, As, Bs, acc, m0, n0);
#pragma unroll
  for (int i = 0; i < 4; ++i)
#pragma unroll
    for (int j = 0; j < 4; ++j)
#pragma unroll
      for (int r = 0; r < 4; ++r) {
        int row = m0 + wm * 64 + i * 16 + quad * 4 + r;
        int col = n0 + wn * 64 + j * 16 + l15;
        C[(size_t)row * C_EMB + col] = declamp(acc[i][j][r], 1e4f);
      }
}

// ---- FIXED-MAX attention step (base-2). K/V/P tiles pitch 64, XOR chunk
//      swizzle: element (row, col=c*8+j) stored at row*64 + ((c^(row&7))*8+j).
//      Round-6 verified structure; only change: bare v_exp_f32 via builtin. ----
__device__ __forceinline__ void attn_step_fm(
    const bf16_t* __restrict__ ks, bf16_t* __restrict__ pw, const bf16_t* __restrict__ vts,
    const bf16x8* qf, float* rsum, f32x4* o,
    bool diag, int k0, int q0, int w, int l15, int quad)
{
  const int xs = l15 & 7;        // row&7 for rows ≡ l15 (mod 16)
  f32x4 sc[4];
#pragma unroll
  for (int nt = 0; nt < 4; ++nt) {
    f32x4 a = {0.f, 0.f, 0.f, 0.f};
#pragma unroll
    for (int s = 0; s < 2; ++s) {
      bf16x8 b = *(const bf16x8*)&ks[(nt * 16 + l15) * 64 + ((((s << 2) + quad) ^ xs) << 3)];
      a = mfma16(qf[s], b, a);
    }
#pragma unroll
    for (int r = 0; r < 4; ++r) a[r] = declamp(a[r], 30.f);   // NaN firewall
    sc[nt] = a;
  }
  if (diag) {
#pragma unroll
    for (int nt = 0; nt < 4; ++nt)
#pragma unroll
      for (int r = 0; r < 4; ++r) {
        int col = k0 + nt * 16 + l15;
        int row = q0 + w * 16 + quad * 4 + r;
        if (col > row) sc[nt][r] = -1e30f;
      }
  }
  // P = exp2(S' - M_FIX2) = exp(S - 9); per-lane row partial sums
#pragma unroll
  for (int nt = 0; nt < 4; ++nt)
#pragma unroll
    for (int r = 0; r < 4; ++r) {
      float pv = fexp2(sc[nt][r] - M_FIX2);
      rsum[r] += pv;
      int row = quad * 4 + r;
      int col = nt * 16 + l15;
      pw[row * 64 + ((((col >> 3) ^ (row & 7)) << 3) | (col & 7))] = (bf16_t)pv;
    }
  // O += P(16x64) @ V(64x128); V from LDS (async-staged, swizzled, 0-conflict)
  __builtin_amdgcn_s_setprio(1);
#pragma unroll
  for (int s = 0; s < 2; ++s) {
    bf16x8 pa = *(const bf16x8*)&pw[l15 * 64 + ((((s << 2) + quad) ^ xs) << 3)];
#pragma unroll
    for (int nt2 = 0; nt2 < 8; ++nt2) {
      bf16x8 vb = *(const bf16x8*)&vts[(nt2 * 16 + l15) * 64 + ((((s << 2) + quad) ^ xs) << 3)];
      o[nt2] = mfma16(pa, vb, o[nt2]);
    }
  }
  __builtin_amdgcn_s_setprio(0);
}

// ---- batch-merged diff attention; K1/K2/V async double-buffered via
//      global_load_lds. LDS = 73728B -> 2 blocks/CU. One barrier per k-tile. ----
__global__ __launch_bounds__(256) void diff_attn2(
    const bf16_t* __restrict__ qp, const bf16_t* __restrict__ kp, const bf16_t* __restrict__ vtp,
    const float* __restrict__ lq1, const float* __restrict__ lk1,
    const float* __restrict__ lq2, const float* __restrict__ lk2,
    bf16_t* __restrict__ outp)
{
  // XCD-local remap: linear id ≡ bh (mod 32) -> all 32 q-blocks of one (b,h)
  // share an XCD (id%8), keeping its ~1MB K/V set in that XCD's L2.
  const int bh = blockIdx.x;
  const int bx = 31 - blockIdx.y;          // longest chains dispatched first
  const int b = bh >> 3, h = bh & 7;
  const int q0 = bx * 64;
  const int tid = threadIdx.x;
  const int lane = tid & 63, w = tid >> 6;
  const int l15 = lane & 15, quad = lane >> 4;
  const size_t bT = (size_t)b * T_SEQ;
  const bf16_t* vth = vtp + (size_t)b * 2097152 + (size_t)(h * 128) * 2048;

  __shared__ bf16_t k1s[2][64 * 64];       // all double-buffered, pitch 64,
  __shared__ bf16_t k2s[2][64 * 64];       // XOR chunk swizzle
  __shared__ bf16_t vts[2][128 * 64];
  __shared__ bf16_t ps[4][16 * 64];

  float e1 = lq1[lane] * lk1[lane];
  float e2 = lq2[lane] * lk2[lane];
#pragma unroll
  for (int mm = 1; mm <= 32; mm <<= 1) { e1 += __shfl_xor(e1, mm); e2 += __shfl_xor(e2, mm); }
  const float lam = expf(declamp(e1, 30.f)) - expf(declamp(e2, 30.f)) + LAMBDA_INIT;

  const int sh1 = 2 * h, sh2 = 2 * h + 1;

  // Staging: per-lane PRE-SWIZZLED global source, linear LDS dest (lane*16B).
  // For any tile with 128B rows: LDS byte o = base + i*1024 + lane*16 ->
  // row r = rbase + i*8 + (lane>>3), chunk c = lane&7; r&7 = lane>>3, so
  // swizzled source chunk = (lane&7) ^ (lane>>3) for K AND V alike.
  const int lrow = lane >> 3;
  const int lchk = (lane & 7) ^ lrow;
  const bf16_t* k1g = kp + (bT + (size_t)(w * 16 + lrow)) * 1024 + sh1 * 64 + (lchk << 3);
  const bf16_t* k2g = kp + (bT + (size_t)(w * 16 + lrow)) * 1024 + sh2 * 64 + (lchk << 3);
  const bf16_t* vg  = vth + (size_t)(w * 32 + lrow) * 2048 + (lchk << 3);

  // prologue: stage tile 0 into buffer 0 (async; drained by first barrier)
  ldsload16(k1g,         &k1s[0][w * 1024]);
  ldsload16(k1g + 8192,  &k1s[0][w * 1024 + 512]);
  ldsload16(k2g,         &k2s[0][w * 1024]);
  ldsload16(k2g + 8192,  &k2s[0][w * 1024 + 512]);
  ldsload16(vg,          &vts[0][w * 2048]);
  ldsload16(vg + 16384,  &vts[0][w * 2048 + 512]);
  ldsload16(vg + 32768,  &vts[0][w * 2048 + 1024]);
  ldsload16(vg + 49152,  &vts[0][w * 2048 + 1536]);

  const int tq = q0 + w * 16 + l15;
  const bf16_t* qrow = qp + (bT + tq) * 1024;
  bf16x8 q1f[2], q2f[2];
#pragma unroll
  for (int s = 0; s < 2; ++s) {
    q1f[s] = *(const bf16x8*)&qrow[sh1 * 64 + s * 32 + quad * 8];
    q2f[s] = *(const bf16x8*)&qrow[sh2 * 64 + s * 32 + quad * 8];
  }

  const f32x4 fz = {0.f, 0.f, 0.f, 0.f};
  f32x4 o1[8], o2[8];
  float rs1[4] = {0, 0, 0, 0}, rs2[4] = {0, 0, 0, 0};
#pragma unroll
  for (int i = 0; i < 8; ++i) { o1[i] = fz; o2[i] = fz; }

  for (int kt = 0; kt <= bx; ++kt) {
    const int cur = kt & 1;
    // __syncthreads drains vmcnt(0): tile kt (issued last iter / prologue) is
    // resident for ALL waves, and all waves finished reading buf[cur^1].
    __syncthreads();
    if (kt < bx) {                         // issue next tile into the freed buffer
      const int nb = cur ^ 1;
      const bf16_t* s1 = k1g + (size_t)(kt + 1) * 65536;
      const bf16_t* s2 = k2g + (size_t)(kt + 1) * 65536;
      const bf16_t* sv = vg + (size_t)(kt + 1) * 64;
      ldsload16(s1,         &k1s[nb][w * 1024]);
      ldsload16(s1 + 8192,  &k1s[nb][w * 1024 + 512]);
      ldsload16(s2,         &k2s[nb][w * 1024]);
      ldsload16(s2 + 8192,  &k2s[nb][w * 1024 + 512]);
      ldsload16(sv,         &vts[nb][w * 2048]);
      ldsload16(sv + 16384, &vts[nb][w * 2048 + 512]);
      ldsload16(sv + 32768, &vts[nb][w * 2048 + 1024]);
      ldsload16(sv + 49152, &vts[nb][w * 2048 + 1536]);
    }
    const int k0 = kt * 64;
    const bool diag = (kt == bx);
    attn_step_fm(&k1s[cur][0], ps[w], &vts[cur][0], q1f, rs1, o1, diag, k0, q0, w, l15, quad);
    attn_step_fm(&k2s[cur][0], ps[w], &vts[cur][0], q2f, rs2, o2, diag, k0, q0, w, l15, quad);
  }

  // epilogue: single shuffle-reduce of row sums, then diff + LN + store
#pragma unroll
  for (int mm = 1; mm <= 8; mm <<= 1)
#pragma unroll
    for (int r = 0; r < 4; ++r) { rs1[r] += __shfl_xor(rs1[r], mm); rs2[r] += __shfl_xor(rs2[r], mm); }
  float i1[4], i2[4];
#pragma unroll
  for (int r = 0; r < 4; ++r) { i1[r] = 1.f / rs1[r]; i2[r] = 1.f / rs2[r]; }
  f32x4 od[8];
  float sum[4] = {0, 0, 0, 0}, sq[4] = {0, 0, 0, 0};
#pragma unroll
  for (int nt2 = 0; nt2 < 8; ++nt2)
#pragma unroll
    for (int r = 0; r < 4; ++r) {
      float v = declamp(o1[nt2][r] * i1[r] - lam * o2[nt2][r] * i2[r], 1e4f);
      od[nt2][r] = v;
      sum[r] += v;
      sq[r] += v * v;
    }
#pragma unroll
  for (int mm = 1; mm <= 8; mm <<= 1)
#pragma unroll
    for (int r = 0; r < 4; ++r) { sum[r] += __shfl_xor(sum[r], mm); sq[r] += __shfl_xor(sq[r], mm); }
  float mu[4], scl[4];
#pragma unroll
  for (int r = 0; r < 4; ++r) {
    mu[r] = sum[r] * (1.0f / 128.0f);
    float var = sq[r] * (1.0f / 128.0f) - mu[r] * mu[r];
    scl[r] = rsqrtf(fmaxf(var, 0.f) + LN_EPS) * ONE_MINUS_LI;
  }
#pragma unroll
  for (int nt2 = 0; nt2 < 8; ++nt2)
#pragma unroll
    for (int r = 0; r < 4; ++r) {
      int trow = q0 + w * 16 + quad * 4 + r;
      outp[(bT + trow) * 1024 + h * 128 + nt2 * 16 + l15] =
          (bf16_t)((od[nt2][r] - mu[r]) * scl[r]);
    }
}

// ==================== FALLBACK PATH (round-4, zero ws) ====================

__device__ __forceinline__ void attn_step(
    const bf16_t* __restrict__ ks, bf16_t* __restrict__ pw, const bf16_t* __restrict__ vts,
    const bf16x8* qf, float* mR, float* lR, f32x4* o,
    bool diag, int k0, int q0, int w, int l15, int quad)
{
  f32x4 sc[4];
#pragma unroll
  for (int nt = 0; nt < 4; ++nt) {
    f32x4 a = {0.f, 0.f, 0.f, 0.f};
#pragma unroll
    for (int s = 0; s < 2; ++s) {
      bf16x8 b = *(const bf16x8*)&ks[(nt * 16 + l15) * 72 + s * 32 + quad * 8];
      a = mfma16(qf[s], b, a);
    }
#pragma unroll
    for (int r = 0; r < 4; ++r) a[r] = declamp(a[r], 1e4f);
    sc[nt] = a;
  }
  if (diag) {
#pragma unroll
    for (int nt = 0; nt < 4; ++nt)
#pragma unroll
      for (int r = 0; r < 4; ++r) {
        int col = k0 + nt * 16 + l15;
        int row = q0 + w * 16 + quad * 4 + r;
        if (col > row) sc[nt][r] = -1e30f;
      }
  }
  float mx[4];
#pragma unroll
  for (int r = 0; r < 4; ++r)
    mx[r] = fmaxf(fmaxf(sc[0][r], sc[1][r]), fmaxf(sc[2][r], sc[3][r]));
#pragma unroll
  for (int mm = 1; mm <= 8; mm <<= 1)
#pragma unroll
    for (int r = 0; r < 4; ++r) mx[r] = fmaxf(mx[r], __shfl_xor(mx[r], mm));

  float mnew[4], alpha[4], rs[4];
#pragma unroll
  for (int r = 0; r < 4; ++r) {
    mnew[r] = fmaxf(mR[r], mx[r]);
    alpha[r] = __expf(mR[r] - mnew[r]);
    rs[r] = 0.f;
  }
#pragma unroll
  for (int nt = 0; nt < 4; ++nt)
#pragma unroll
    for (int r = 0; r < 4; ++r) {
      float pv = __expf(sc[nt][r] - mnew[r]);
      rs[r] += pv;
      pw[(quad * 4 + r) * 72 + nt * 16 + l15] = (bf16_t)pv;
    }
#pragma unroll
  for (int mm = 1; mm <= 8; mm <<= 1)
#pragma unroll
    for (int r = 0; r < 4; ++r) rs[r] += __shfl_xor(rs[r], mm);
#pragma unroll
  for (int r = 0; r < 4; ++r) {
    lR[r] = lR[r] * alpha[r] + rs[r];
    mR[r] = mnew[r];
  }
#pragma unroll
  for (int nt2 = 0; nt2 < 8; ++nt2)
#pragma unroll
    for (int r = 0; r < 4; ++r) o[nt2][r] *= alpha[r];
#pragma unroll
  for (int s = 0; s < 2; ++s) {
    bf16x8 pa = *(const bf16x8*)&pw[l15 * 72 + s * 32 + quad * 8];
#pragma unroll
    for (int nt2 = 0; nt2 < 8; ++nt2) {
      bf16x8 vb = *(const bf16x8*)&vts[(nt2 * 16 + l15) * 72 + s * 32 + quad * 8];
      o[nt2] = mfma16(pa, vb, o[nt2]);
    }
  }
}

template<bool A_F32, bool OUT_F32>
__global__ __launch_bounds__(256) void gemm_bt(
    const void* __restrict__ Ap,
    const float* __restrict__ W0, const float* __restrict__ W1, const float* __restrict__ W2,
    void* __restrict__ Cp0, void* __restrict__ Cp1, void* __restrict__ Cp2)
{
  const float* W = (blockIdx.z == 0) ? W0 : ((blockIdx.z == 1) ? W1 : W2);
  void*       Cv = (blockIdx.z == 0) ? Cp0 : ((blockIdx.z == 1) ? Cp1 : Cp2);
  const int K = C_EMB, N = C_EMB;
  const int n0 = blockIdx.x * 128, m0 = blockIdx.y * 128;
  __shared__ bf16_t As[128 * 40];
  __shared__ bf16_t Bs[128 * 40];
  const int tid = threadIdx.x;
  const int lane = tid & 63, w = tid >> 6;
  const int wm = w >> 1, wn = w & 1;
  const int l15 = lane & 15, quad = lane >> 4;
  const f32x4 fz = {0.f, 0.f, 0.f, 0.f};
  f32x4 acc[4][4];
#pragma unroll
  for (int i = 0; i < 4; ++i)
#pragma unroll
    for (int j = 0; j < 4; ++j) acc[i][j] = fz;

  for (int k0 = 0; k0 < K; k0 += 32) {
    if constexpr (A_F32) {
      const float* Af = (const float*)Ap;
#pragma unroll
      for (int i = 0; i < 4; ++i) {
        int c = tid + i * 256;
        int r = c >> 3, c4 = (c & 7) * 4;
        f32x4 v = *(const f32x4*)&Af[(size_t)(m0 + r) * K + k0 + c4];
        bf16x4 bv;
#pragma unroll
        for (int j = 0; j < 4; ++j) bv[j] = (bf16_t)v[j];
        *(bf16x4*)&As[r * 40 + c4] = bv;
      }
    } else {
      const bf16_t* Ab = (const bf16_t*)Ap;
#pragma unroll
      for (int i = 0; i < 2; ++i) {
        int c = tid + i * 256;
        int r = c >> 2, c8 = (c & 3) * 8;
        *(bf16x8*)&As[r * 40 + c8] = *(const bf16x8*)&Ab[(size_t)(m0 + r) * K + k0 + c8];
      }
    }
#pragma unroll
    for (int i = 0; i < 4; ++i) {
      int c = tid + i * 256;
      int r = c >> 3, c4 = (c & 7) * 4;
      f32x4 v = *(const f32x4*)&W[(size_t)(n0 + r) * K + k0 + c4];
      bf16x4 bv;
#pragma unroll
      for (int j = 0; j < 4; ++j) bv[j] = (bf16_t)v[j];
      *(bf16x4*)&Bs[r * 40 + c4] = bv;
    }
    __syncthreads();
    bf16x8 af[4], bfr[4];
#pragma unroll
    for (int i = 0; i < 4; ++i)
      af[i] = *(const bf16x8*)&As[(wm * 64 + i * 16 + l15) * 40 + quad * 8];
#pragma unroll
    for (int j = 0; j < 4; ++j)
      bfr[j] = *(const bf16x8*)&Bs[(wn * 64 + j * 16 + l15) * 40 + quad * 8];
#pragma unroll
    for (int i = 0; i < 4; ++i)
#pragma unroll
      for (int j = 0; j < 4; ++j) acc[i][j] = mfma16(af[i], bfr[j], acc[i][j]);
    __syncthreads();
  }
#pragma unroll
  for (int i = 0; i < 4; ++i)
#pragma unroll
    for (int j = 0; j < 4; ++j)
#pragma unroll
      for (int r = 0; r < 4; ++r) {
        int row = m0 + wm * 64 + i * 16 + quad * 4 + r;
        int col = n0 + wn * 64 + j * 16 + l15;
        float v = declamp(acc[i][j][r], 1e4f);
        if constexpr (OUT_F32) ((float*)Cv)[(size_t)row * N + col] = v;
        else                   ((bf16_t*)Cv)[(size_t)row * N + col] = (bf16_t)v;
      }
}

__global__ __launch_bounds__(256) void rope_rms(bf16_t* __restrict__ arr, int is_q)
{
  const int tid = threadIdx.x;
  const int g = blockIdx.x * 16 + (tid >> 4);
  const int l16 = tid & 15;
  const int t = (g >> 4) & (T_SEQ - 1);
  bf16_t* p = arr + (size_t)g * 64 + l16 * 4;
  bf16x4 xv = *(const bf16x4*)p;
  float x[4];
#pragma unroll
  for (int j = 0; j < 4; ++j) x[j] = (float)xv[j];
  float ss = x[0]*x[0] + x[1]*x[1] + x[2]*x[2] + x[3]*x[3];
#pragma unroll
  for (int mm = 1; mm <= 8; mm <<= 1) ss += __shfl_xor(ss, mm);
  const float rn = rsqrtf(fmaxf(ss, 0.f) * (1.0f / 64.0f) + RMS_EPS);
  float nrm[4], prt[4];
#pragma unroll
  for (int j = 0; j < 4; ++j) nrm[j] = x[j] * rn;
#pragma unroll
  for (int j = 0; j < 4; ++j) prt[j] = __shfl_xor(nrm[j], 8);
  const int ib = (l16 & 7) * 4;
  const float sgn = (l16 < 8) ? 1.f : -1.f;
  const float scale = is_q ? 0.125f : 1.0f;
  bf16x4 ov;
#pragma unroll
  for (int j = 0; j < 4; ++j) {
    int i = ib + j;
    float invf = __expf(-(float)i * 0.28782313662425575f);
    float ang = (float)t * invf;
    float c, s;
    __sincosf(ang, &s, &c);
    ov[j] = (bf16_t)((nrm[j] * c + sgn * prt[j] * s) * scale);
  }
  *(bf16x4*)p = ov;
}

__global__ __launch_bounds__(256) void diff_attn(
    const bf16_t* qp, const bf16_t* __restrict__ kp, const bf16_t* __restrict__ vp,
    const float* __restrict__ lq1, const float* __restrict__ lk1,
    const float* __restrict__ lq2, const float* __restrict__ lk2,
    bf16_t* outp)
{
  const int bx = blockIdx.x;
  const int h = blockIdx.y;
  const int q0 = bx * 64;
  const int tid = threadIdx.x;
  const int lane = tid & 63, w = tid >> 6;
  const int l15 = lane & 15, quad = lane >> 4;

  __shared__ bf16_t k1s[64 * 72];
  __shared__ bf16_t k2s[64 * 72];
  __shared__ bf16_t vts[128 * 72];
  __shared__ bf16_t ps[4][16 * 72];

  float e1 = lq1[lane] * lk1[lane];
  float e2 = lq2[lane] * lk2[lane];
#pragma unroll
  for (int mm = 1; mm <= 32; mm <<= 1) { e1 += __shfl_xor(e1, mm); e2 += __shfl_xor(e2, mm); }
  const float lam = expf(declamp(e1, 30.f)) - expf(declamp(e2, 30.f)) + LAMBDA_INIT;

  const int sh1 = 2 * h, sh2 = 2 * h + 1;
  const int tq = q0 + w * 16 + l15;
  const bf16_t* qrow = qp + (size_t)tq * 1024;
  bf16x8 q1f[2], q2f[2];
#pragma unroll
  for (int s = 0; s < 2; ++s) {
    q1f[s] = *(const bf16x8*)&qrow[sh1 * 64 + s * 32 + quad * 8];
    q2f[s] = *(const bf16x8*)&qrow[sh2 * 64 + s * 32 + quad * 8];
  }
  const f32x4 fz = {0.f, 0.f, 0.f, 0.f};
  f32x4 o1[8], o2[8];
  float m1[4], l1[4], m2[4], l2[4];
#pragma unroll
  for (int i = 0; i < 8; ++i) { o1[i] = fz; o2[i] = fz; }
#pragma unroll
  for (int r = 0; r < 4; ++r) { m1[r] = -1e30f; m2[r] = -1e30f; l1[r] = 0.f; l2[r] = 0.f; }

  for (int kt = 0; kt <= bx; ++kt) {
    const int k0 = kt * 64;
    __syncthreads();
#pragma unroll
    for (int i = 0; i < 2; ++i) {
      int c = tid + i * 256;
      int r = c >> 3, c8 = (c & 7) * 8;
      const bf16_t* krow = kp + (size_t)(k0 + r) * 1024;
      *(bf16x8*)&k1s[r * 72 + c8] = *(const bf16x8*)&krow[sh1 * 64 + c8];
      *(bf16x8*)&k2s[r * 72 + c8] = *(const bf16x8*)&krow[sh2 * 64 + c8];
    }
#pragma unroll
    for (int i = 0; i < 4; ++i) {
      int c = tid + i * 256;
      int r = c >> 4, d8 = (c & 15) * 8;
      bf16x8 vv = *(const bf16x8*)&vp[(size_t)(k0 + r) * 1024 + h * 128 + d8];
#pragma unroll
      for (int jj = 0; jj < 8; ++jj) vts[(d8 + jj) * 72 + r] = vv[jj];
    }
    __syncthreads();
    const bool diag = (kt == bx);
    attn_step(k1s, ps[w], vts, q1f, m1, l1, o1, diag, k0, q0, w, l15, quad);
    attn_step(k2s, ps[w], vts, q2f, m2, l2, o2, diag, k0, q0, w, l15, quad);
  }
  float i1[4], i2[4];
#pragma unroll
  for (int r = 0; r < 4; ++r) { i1[r] = 1.f / l1[r]; i2[r] = 1.f / l2[r]; }
  f32x4 od[8];
  float sum[4] = {0, 0, 0, 0}, sq[4] = {0, 0, 0, 0};
#pragma unroll
  for (int nt2 = 0; nt2 < 8; ++nt2)
#pragma unroll
    for (int r = 0; r < 4; ++r) {
      float v = declamp(o1[nt2][r] * i1[r] - lam * o2[nt2][r] * i2[r], 1e4f);
      od[nt2][r] = v;
      sum[r] += v;
      sq[r] += v * v;
    }
#pragma unroll
  for (int mm = 1; mm <= 8; mm <<= 1)
#pragma unroll
    for (int r = 0; r < 4; ++r) { sum[r] += __shfl_xor(sum[r], mm); sq[r] += __shfl_xor(sq[r], mm); }
  float mu[4], scl[4];
#pragma unroll
  for (int r = 0; r < 4; ++r) {
    mu[r] = sum[r] * (1.0f / 128.0f);
    float var = sq[r] * (1.0f / 128.0f) - mu[r] * mu[r];
    scl[r] = rsqrtf(fmaxf(var, 0.f) + LN_EPS) * ONE_MINUS_LI;
  }
#pragma unroll
  for (int nt2 = 0; nt2 < 8; ++nt2)
#pragma unroll
    for (int r = 0; r < 4; ++r) {
      int trow = q0 + w * 16 + quad * 4 + r;
      outp[(size_t)trow * 1024 + h * 128 + nt2 * 16 + l15] =
          (bf16_t)((od[nt2][r] - mu[r]) * scl[r]);
    }
}

// ==================== launch ====================
extern "C" void kernel_launch(void* const* d_in, const int* in_sizes, int n_in,
                              void* d_out, int out_size, void* d_ws, size_t ws_size,
                              hipStream_t stream) {
  const float* x     = (const float*)d_in[0];
  const float* Wq    = (const float*)d_in[1];
  const float* Wk    = (const float*)d_in[2];
  const float* Wv    = (const float*)d_in[3];
  const float* Wproj = (const float*)d_in[4];
  const float* lq1   = (const float*)d_in[5];
  const float* lk1   = (const float*)d_in[6];
  const float* lq2   = (const float*)d_in[7];
  const float* lk2   = (const float*)d_in[8];
  float* O = (float*)d_out;
  const size_t R = (size_t)T_SEQ * C_EMB;

  if (ws_size >= (size_t)40 * 1024 * 1024) {
    // ---------- FAST PATH ----------
    bf16_t* wsb = (bf16_t*)d_ws;
    bf16_t* xb  = wsb;                       // [0, 8M elems) ; reused as attn-out
    bf16_t* wqb = wsb + 8388608;
    bf16_t* wkb = wqb + 1048576;
    bf16_t* wvb = wkb + 1048576;
    bf16_t* wpb = wvb + 1048576;
    bf16_t* vt  = wpb + 1048576;             // [12M, 20M elems) = 16MB
    bf16_t* qo  = (bf16_t*)d_out;            // d_out low half
    bf16_t* ko  = qo + 8388608;              // d_out high half
    bf16_t* a   = xb;                        // attn-out over dead xb

    cvt_all<<<12288, 256, 0, stream>>>(x, Wq, Wk, Wv, Wproj, xb, wqb, wkb, wvb, wpb);
    gemm_qkv<<<dim3(8, 64, 3), 256, 0, stream>>>(xb, wqb, wkb, wvb, qo, ko, vt);
    diff_attn2<<<dim3(32, 32), 256, 0, stream>>>(qo, ko, vt, lq1, lk1, lq2, lk2, a);
    gemm_proj<<<dim3(8, 64), 256, 0, stream>>>(a, wpb, O);
  } else {
    // ---------- FALLBACK (round-4 proven, zero ws) ----------
    char* Ob = (char*)d_out;
    char* Xb = (char*)d_in[0];
    const size_t MB4 = (size_t)1 << 22;
    bf16_t* qb[4] = { (bf16_t*)(Ob + 2*MB4), (bf16_t*)(Ob + 5*MB4),
                      (bf16_t*)(Xb + 0*MB4), (bf16_t*)(Xb + 3*MB4) };
    bf16_t* kb[4] = { (bf16_t*)(Ob + 3*MB4), (bf16_t*)(Ob + 6*MB4),
                      (bf16_t*)(Xb + 1*MB4), (bf16_t*)(Xb + 4*MB4) };
    bf16_t* vb[4] = { (bf16_t*)(Ob + 4*MB4), (bf16_t*)(Ob + 7*MB4),
                      (bf16_t*)(Xb + 2*MB4), (bf16_t*)(Xb + 5*MB4) };
    for (int b = 0; b < 4; ++b) {
      const float* xbp = x + (size_t)b * R;
      gemm_bt<true, false><<<dim3(8, 16, 3), 256, 0, stream>>>(
          xbp, Wq, Wk, Wv, qb[b], kb[b], vb[b]);
      rope_rms<<<2048, 256, 0, stream>>>(qb[b], 1);
      rope_rms<<<2048, 256, 0, stream>>>(kb[b], 0);
      diff_attn<<<dim3(32, 8), 256, 0, stream>>>(qb[b], kb[b], vb[b],
                                                 lq1, lk1, lq2, lk2, qb[b]);
      gemm_bt<false, true><<<dim3(8, 16, 1), 256, 0, stream>>>(
          qb[b], Wproj, Wproj, Wproj, O + (size_t)b * R, nullptr, nullptr);
    }
  }
}

// Round 10
// 285.568 us; speedup vs baseline: 1.0719x; 1.0199x over previous
//
#include <hip/hip_runtime.h>
#include <hip/hip_bf16.h>
#include <math.h>

// Differential causal self-attention. ALL I/O float32; internal bf16 MFMA.
// FAST PATH (ws_size >= 40MB): batch-merged launches, 4 dispatches.
//   ws: [0,16M) xb (x as bf16; reused as attn-out after QKV consumes it)
//       [16M,24M) Wq,Wk,Wv,Wproj as bf16 (2MB each)
//       [24M,40M) vt = V transposed per batch: vt[b][dim 0..1023][t 0..2047]
//   d_out: [0,16M) q bf16, [16M,32M) k bf16 (dead before proj writes f32)
// Attention: FIXED-max softmax in BASE-2 (q pre-scaled by log2e; P =
//   exp2(S' - 9*log2e) = exp(S-9); rmsnorm bounds |S|<=8.05).
// Round 17: FUSED PV on the round-16 best (291us; exp2-direct confirmed
//   -3us, VALU cycles -8%). r14 post-mortem: PV fusion was ~neutral there
//   only because lib-exp2f (+14.4 VALU-units) dominated; MFMA-work was
//   identical. Now isolated: QK+softmax for both components first (ps
//   reused serially; per-wave DS ops are in-order; numerics verified in
//   r14's passing run), then ONE PV loop reading each V fragment once for
//   o1+o2: -16 ds_read_b128/step/wave, 32-MFMA setprio cluster.
//   VGPR 96 -> ~110, MUST stay <128 (r5 cliff).
// Round 13 (kept): RMSNorm+RoPE fused in gemm_qkv epilogue; diff_attn2 =
//   async gload_lds dbuf K1/K2/V, 1 barrier/k-tile, grid (32,32), 2 blk/CU.
// Round 10 (kept): GEMMs on async gload_lds dbuf, 1 barrier/step, XCD tiles.
// Round 8 (kept): XCD-local bh=blockIdx.x remap (FETCH 125->38MB).
// Ledger: lib exp2f forbidden (r14); pair-balancing regressed (r12);
//   LDS not the occupancy binder at 73728 (r11); reg-staging regressed (r11).
// FALLBACK (small ws): round-4 proven per-batch pipeline, zero ws usage.

typedef __bf16 bf16_t;
typedef __bf16 bf16x8 __attribute__((ext_vector_type(8)));
typedef __bf16 bf16x4 __attribute__((ext_vector_type(4)));
typedef float  f32x4  __attribute__((ext_vector_type(4)));

#define T_SEQ 2048
#define C_EMB 1024
static constexpr float LAMBDA_INIT = 0.6192834728526787f;   // 0.8 - 0.6*exp(-1.2)
static constexpr float ONE_MINUS_LI = 0.3807165271473213f;
static constexpr float RMS_EPS = 1.1920928955078125e-07f;
static constexpr float LN_EPS = 1e-5f;
static constexpr float M_FIX2 = 12.984255368000671f;  // 9 * log2(e): fixed max, base-2
static constexpr float QSCL2  = 0.18033688011112042f; // 0.125 * log2(e)

__device__ __forceinline__ f32x4 mfma16(bf16x8 a, bf16x8 b, f32x4 c) {
  return __builtin_amdgcn_mfma_f32_16x16x32_bf16(a, b, c, 0, 0, 0);
}
__device__ __forceinline__ float declamp(float v, float lim) {
  return fminf(fmaxf(v, -lim), lim);   // IEEE min/max: NaN firewall too
}
__device__ __forceinline__ float fexp2(float x) {
  return __builtin_amdgcn_exp2f(x);    // bare v_exp_f32 (no OCML fixup path)
}
// async global->LDS, 16B per lane; lds dest must be wave-uniform base (+lane*16)
__device__ __forceinline__ void ldsload16(const bf16_t* g, bf16_t* l) {
  __builtin_amdgcn_global_load_lds(
      (const __attribute__((address_space(1))) void*)g,
      (__attribute__((address_space(3))) void*)l, 16, 0, 0);
}

// ==================== FAST PATH ====================

// ---- one-shot f32 -> bf16 convert: x (8M) + 4 weights (1M each) ----
__global__ __launch_bounds__(256) void cvt_all(
    const float* __restrict__ x,  const float* __restrict__ Wq,
    const float* __restrict__ Wk, const float* __restrict__ Wv,
    const float* __restrict__ Wp,
    bf16_t* __restrict__ xb,  bf16_t* __restrict__ wqb, bf16_t* __restrict__ wkb,
    bf16_t* __restrict__ wvb, bf16_t* __restrict__ wpb)
{
  size_t i4 = ((size_t)blockIdx.x * 256 + threadIdx.x) * 4;
  const float* s; bf16_t* d; size_t off;
  if      (i4 <  8388608) { s = x;  d = xb;  off = i4; }
  else if (i4 <  9437184) { s = Wq; d = wqb; off = i4 - 8388608; }
  else if (i4 < 10485760) { s = Wk; d = wkb; off = i4 - 9437184; }
  else if (i4 < 11534336) { s = Wv; d = wvb; off = i4 - 10485760; }
  else                    { s = Wp; d = wpb; off = i4 - 11534336; }
  f32x4 v = *(const f32x4*)(s + off);
  bf16x4 bv;
#pragma unroll
  for (int j = 0; j < 4; ++j) bv[j] = (bf16_t)v[j];
  *(bf16x4*)(d + off) = bv;
}

// ---- async GEMM mainloop: acc = A(128 rows) @ W(128 rows)^T over K=1024.
//      Double-buffered global_load_lds, 1 barrier/step, chunk-XOR swizzle:
//      row r chunk c (16B) stored at linear r*32 + (c ^ ((r>>1)&3))*8. ----
__device__ __forceinline__ void gemm_core(
    const bf16_t* __restrict__ A, const bf16_t* __restrict__ W,
    bf16_t (*As)[4096], bf16_t (*Bs)[4096], f32x4 acc[4][4], int m0, int n0)
{
  const int tid = threadIdx.x;
  const int lane = tid & 63, w = tid >> 6;
  const int wm = w >> 1, wn = w & 1;
  const int l15 = lane & 15, quad = lane >> 4;

  // Stage source (pre-swizzled): wave w call i covers rows w*32+i*16+(lane>>2),
  // stored chunk lane&3 must hold source chunk (lane&3)^((lane>>3)&3).
  const int srow = lane >> 2;
  const int schk = (lane & 3) ^ ((lane >> 3) & 3);
  const bf16_t* Ag = A + (size_t)(m0 + w * 32 + srow) * C_EMB + schk * 8;
  const bf16_t* Wg = W + (size_t)(n0 + w * 32 + srow) * C_EMB + schk * 8;

  // prologue: stage k-step 0 into buffer 0
  ldsload16(Ag,              &As[0][w * 1024]);
  ldsload16(Ag + 16 * C_EMB, &As[0][w * 1024 + 512]);
  ldsload16(Wg,              &Bs[0][w * 1024]);
  ldsload16(Wg + 16 * C_EMB, &Bs[0][w * 1024 + 512]);

  for (int ks = 0; ks < 32; ++ks) {
    const int cur = ks & 1;
    // __syncthreads drains vmcnt(0): step ks resident; buf[cur^1] free.
    __syncthreads();
    if (ks < 31) {
      const int nb = cur ^ 1;
      const bf16_t* a2 = Ag + (ks + 1) * 32;
      const bf16_t* w2 = Wg + (ks + 1) * 32;
      ldsload16(a2,              &As[nb][w * 1024]);
      ldsload16(a2 + 16 * C_EMB, &As[nb][w * 1024 + 512]);
      ldsload16(w2,              &Bs[nb][w * 1024]);
      ldsload16(w2 + 16 * C_EMB, &Bs[nb][w * 1024 + 512]);
    }
    bf16x8 af[4], bfr[4];
#pragma unroll
    for (int i = 0; i < 4; ++i) {
      int ra = wm * 64 + i * 16 + l15;
      int ca = quad ^ ((ra >> 1) & 3);
      af[i] = *(const bf16x8*)&As[cur][ra * 32 + ca * 8];
    }
#pragma unroll
    for (int j = 0; j < 4; ++j) {
      int rb = wn * 64 + j * 16 + l15;
      int cb = quad ^ ((rb >> 1) & 3);
      bfr[j] = *(const bf16x8*)&Bs[cur][rb * 32 + cb * 8];
    }
    __builtin_amdgcn_s_setprio(1);
#pragma unroll
    for (int i = 0; i < 4; ++i)
#pragma unroll
      for (int j = 0; j < 4; ++j) acc[i][j] = mfma16(af[i], bfr[j], acc[i][j]);
    __builtin_amdgcn_s_setprio(0);
  }
}

// XCD-contiguous tile remap for grid (8, 64, z): linear id ≡ bx (mod 8) picks
// the XCD, so XCD bx owns m-tiles [bx*8, bx*8+8) x all 8 n-tiles: each A panel
// is HBM-fetched once per XCD; the 2MB W stays L2-resident.
__device__ __forceinline__ void xcd_tiles(int& m0, int& n0) {
  m0 = (blockIdx.x * 8 + (blockIdx.y >> 3)) * 128;
  n0 = (blockIdx.y & 7) * 128;
}

// ---- QKV gemm over all batches (M=8192). z=0 q, z=1 k: RMSNorm+RoPE fused
//      in the epilogue (tile cols = whole 64-dim head groups; rope pair
//      d<->d+32 is j<->j+2 lane-local; RMS = 4 sq + shfl over l15).
//      q additionally scaled by log2(e)/8 (base-2 softmax upstream fold).
//      z=2 v written TRANSPOSED: vt[b][col][t] (bf16x4 along t, no LDS) ----
__global__ __launch_bounds__(256) void gemm_qkv(
    const bf16_t* __restrict__ A,
    const bf16_t* __restrict__ Wqb, const bf16_t* __restrict__ Wkb, const bf16_t* __restrict__ Wvb,
    bf16_t* __restrict__ qo, bf16_t* __restrict__ ko, bf16_t* __restrict__ vt)
{
  const int z = blockIdx.z;
  const bf16_t* W = (z == 0) ? Wqb : ((z == 1) ? Wkb : Wvb);
  int m0, n0; xcd_tiles(m0, n0);
  __shared__ bf16_t As[2][4096];
  __shared__ bf16_t Bs[2][4096];
  const int lane = threadIdx.x & 63, w = threadIdx.x >> 6;
  const int wm = w >> 1, wn = w & 1;
  const int l15 = lane & 15, quad = lane >> 4;
  const f32x4 fz = {0.f, 0.f, 0.f, 0.f};
  f32x4 acc[4][4];
#pragma unroll
  for (int i = 0; i < 4; ++i)
#pragma unroll
    for (int j = 0; j < 4; ++j) acc[i][j] = fz;
  gemm_core(A, W, As, Bs, acc, m0, n0);

  if (z < 2) {
    bf16_t* C = z ? ko : qo;
    const float scale = z ? 1.0f : QSCL2;        // q gets log2(e)/sqrt(64)
#pragma unroll
    for (int i = 0; i < 4; ++i)
#pragma unroll
      for (int r = 0; r < 4; ++r) {
        float v0 = acc[i][0][r], v1 = acc[i][1][r];
        float v2 = acc[i][2][r], v3 = acc[i][3][r];
        float ss = v0 * v0 + v1 * v1 + v2 * v2 + v3 * v3;
#pragma unroll
        for (int mm = 1; mm <= 8; mm <<= 1) ss += __shfl_xor(ss, mm);
        const float rn = rsqrtf(fmaxf(ss, 0.f) * (1.0f / 64.0f) + RMS_EPS);
        const int row = m0 + wm * 64 + i * 16 + quad * 4 + r;
        const float t = (float)(row & (T_SEQ - 1));
        const float n0v = v0 * rn, n1v = v1 * rn, n2v = v2 * rn, n3v = v3 * rn;
        float c0, s0, c1, s1;
        __sincosf(t * __expf(-(float)l15 * 0.28782313662425575f), &s0, &c0);
        __sincosf(t * __expf(-(float)(16 + l15) * 0.28782313662425575f), &s1, &c1);
        const float o0 = (n0v * c0 + n2v * s0) * scale;   // d = l15
        const float o1 = (n1v * c1 + n3v * s1) * scale;   // d = 16+l15
        const float o2 = (n2v * c0 - n0v * s0) * scale;   // d = 32+l15
        const float o3 = (n3v * c1 - n1v * s1) * scale;   // d = 48+l15
        const size_t base = (size_t)row * C_EMB + n0 + wn * 64 + l15;
        C[base]      = (bf16_t)declamp(o0, 1e4f);
        C[base + 16] = (bf16_t)declamp(o1, 1e4f);
        C[base + 32] = (bf16_t)declamp(o2, 1e4f);
        C[base + 48] = (bf16_t)declamp(o3, 1e4f);
      }
  } else {
#pragma unroll
    for (int i = 0; i < 4; ++i)
#pragma unroll
      for (int j = 0; j < 4; ++j) {
        int row = m0 + wm * 64 + i * 16 + quad * 4;   // multiple of 4, same batch
        int col = n0 + wn * 64 + j * 16 + l15;
        bf16x4 pv;
#pragma unroll
        for (int r = 0; r < 4; ++r) pv[r] = (bf16_t)declamp(acc[i][j][r], 1e4f);
        size_t idx = (size_t)(row >> 11) * 2097152 + (size_t)col * 2048 + (row & 2047);
        *(bf16x4*)&vt[idx] = pv;
      }
  }
}

// ---- proj gemm: bf16 A/W -> f32 out ----
__global__ __launch_bounds__(256) void gemm_proj(
    const bf16_t* __restrict__ A, const bf16_t* __restrict__ Wpb, float* __restrict__ C)
{
  int m0, n0; xcd_tiles(m0, n0);
  __shared__ bf16_t As[2][4096];
  __shared__ bf16_t Bs[2][4096];
  const int lane = threadIdx.x & 63, w = threadIdx.x >> 6;
  const int wm = w >> 1, wn = w & 1;
  const int l15 = lane & 15, quad = lane >> 4;
  const f32x4 fz = {0.f, 0.f, 0.f, 0.f};
  f32x4 acc[4][4];
#pragma unroll
  for (int i = 0; i < 4; ++i)
#pragma unroll
    for (int j = 0; j < 4; ++j) acc[i][j] = fz;
  gemm_core(A, Wpb, As, Bs, acc, m0, n0);
#pragma unroll
  for (int i = 0; i < 4; ++i)
#pragma unroll
    for (int j = 0; j < 4; ++j)
#pragma unroll
      for (int r = 0; r < 4; ++r) {
        int row = m0 + wm * 64 + i * 16 + quad * 4 + r;
        int col = n0 + wn * 64 + j * 16 + l15;
        C[(size_t)row * C_EMB + col] = declamp(acc[i][j][r], 1e4f);
      }
}

// ---- FIXED-MAX QK^T + base-2 softmax for one component. K/P tiles pitch 64,
//      XOR chunk swizzle: (row, col=c*8+j) at row*64 + ((c ^ (row&7))*8 + j).
//      Writes P to wave-private pw, then reads back PV A-fragments (pa).
//      Per-wave DS ops are in-order: pa readback completes before the next
//      component's P overwrites pw (verified numerics, r14 run). ----
__device__ __forceinline__ void qk_sm_fm(
    const bf16_t* __restrict__ ks, bf16_t* __restrict__ pw,
    const bf16x8* qf, float* rsum, bf16x8* pa,
    bool diag, int k0, int q0, int w, int l15, int quad)
{
  const int xs = l15 & 7;        // row&7 for rows ≡ l15 (mod 16)
  f32x4 sc[4];
#pragma unroll
  for (int nt = 0; nt < 4; ++nt) {
    f32x4 a = {0.f, 0.f, 0.f, 0.f};
#pragma unroll
    for (int s = 0; s < 2; ++s) {
      bf16x8 b = *(const bf16x8*)&ks[(nt * 16 + l15) * 64 + ((((s << 2) + quad) ^ xs) << 3)];
      a = mfma16(qf[s], b, a);
    }
#pragma unroll
    for (int r = 0; r < 4; ++r) a[r] = declamp(a[r], 30.f);   // NaN firewall
    sc[nt] = a;
  }
  if (diag) {
#pragma unroll
    for (int nt = 0; nt < 4; ++nt)
#pragma unroll
      for (int r = 0; r < 4; ++r) {
        int col = k0 + nt * 16 + l15;
        int row = q0 + w * 16 + quad * 4 + r;
        if (col > row) sc[nt][r] = -1e30f;
      }
  }
  // P = exp2(S' - M_FIX2) = exp(S - 9); per-lane row partial sums
#pragma unroll
  for (int nt = 0; nt < 4; ++nt)
#pragma unroll
    for (int r = 0; r < 4; ++r) {
      float pv = fexp2(sc[nt][r] - M_FIX2);
      rsum[r] += pv;
      int row = quad * 4 + r;
      int col = nt * 16 + l15;
      pw[row * 64 + ((((col >> 3) ^ (row & 7)) << 3) | (col & 7))] = (bf16_t)pv;
    }
  // read back PV A-fragments (wave-private buffer: no barrier, lgkm only)
#pragma unroll
  for (int s = 0; s < 2; ++s)
    pa[s] = *(const bf16x8*)&pw[l15 * 64 + ((((s << 2) + quad) ^ xs) << 3)];
}

// ---- batch-merged diff attention; K1/K2/V async double-buffered via
//      global_load_lds. LDS = 73728B -> 2 blocks/CU. One barrier per k-tile.
//      FUSED PV: both components' P computed first, one V read feeds both. ----
__global__ __launch_bounds__(256) void diff_attn2(
    const bf16_t* __restrict__ qp, const bf16_t* __restrict__ kp, const bf16_t* __restrict__ vtp,
    const float* __restrict__ lq1, const float* __restrict__ lk1,
    const float* __restrict__ lq2, const float* __restrict__ lk2,
    bf16_t* __restrict__ outp)
{
  // XCD-local remap: linear id ≡ bh (mod 32) -> all 32 q-blocks of one (b,h)
  // share an XCD (id%8), keeping its ~1MB K/V set in that XCD's L2.
  const int bh = blockIdx.x;
  const int bx = 31 - blockIdx.y;          // longest chains dispatched first
  const int b = bh >> 3, h = bh & 7;
  const int q0 = bx * 64;
  const int tid = threadIdx.x;
  const int lane = tid & 63, w = tid >> 6;
  const int l15 = lane & 15, quad = lane >> 4;
  const size_t bT = (size_t)b * T_SEQ;
  const bf16_t* vth = vtp + (size_t)b * 2097152 + (size_t)(h * 128) * 2048;

  __shared__ bf16_t k1s[2][64 * 64];       // all double-buffered, pitch 64,
  __shared__ bf16_t k2s[2][64 * 64];       // XOR chunk swizzle
  __shared__ bf16_t vts[2][128 * 64];
  __shared__ bf16_t ps[4][16 * 64];        // wave-private P scratch

  float e1 = lq1[lane] * lk1[lane];
  float e2 = lq2[lane] * lk2[lane];
#pragma unroll
  for (int mm = 1; mm <= 32; mm <<= 1) { e1 += __shfl_xor(e1, mm); e2 += __shfl_xor(e2, mm); }
  const float lam = expf(declamp(e1, 30.f)) - expf(declamp(e2, 30.f)) + LAMBDA_INIT;

  const int sh1 = 2 * h, sh2 = 2 * h + 1;

  // Staging: per-lane PRE-SWIZZLED global source, linear LDS dest (lane*16B).
  // For any tile with 128B rows: LDS byte o = base + i*1024 + lane*16 ->
  // row r = rbase + i*8 + (lane>>3), chunk c = lane&7; r&7 = lane>>3, so
  // swizzled source chunk = (lane&7) ^ (lane>>3) for K AND V alike.
  const int lrow = lane >> 3;
  const int lchk = (lane & 7) ^ lrow;
  const bf16_t* k1g = kp + (bT + (size_t)(w * 16 + lrow)) * 1024 + sh1 * 64 + (lchk << 3);
  const bf16_t* k2g = kp + (bT + (size_t)(w * 16 + lrow)) * 1024 + sh2 * 64 + (lchk << 3);
  const bf16_t* vg  = vth + (size_t)(w * 32 + lrow) * 2048 + (lchk << 3);

  // prologue: stage tile 0 into buffer 0 (async; drained by first barrier)
  ldsload16(k1g,         &k1s[0][w * 1024]);
  ldsload16(k1g + 8192,  &k1s[0][w * 1024 + 512]);
  ldsload16(k2g,         &k2s[0][w * 1024]);
  ldsload16(k2g + 8192,  &k2s[0][w * 1024 + 512]);
  ldsload16(vg,          &vts[0][w * 2048]);
  ldsload16(vg + 16384,  &vts[0][w * 2048 + 512]);
  ldsload16(vg + 32768,  &vts[0][w * 2048 + 1024]);
  ldsload16(vg + 49152,  &vts[0][w * 2048 + 1536]);

  const int tq = q0 + w * 16 + l15;
  const bf16_t* qrow = qp + (bT + tq) * 1024;
  bf16x8 q1f[2], q2f[2];
#pragma unroll
  for (int s = 0; s < 2; ++s) {
    q1f[s] = *(const bf16x8*)&qrow[sh1 * 64 + s * 32 + quad * 8];
    q2f[s] = *(const bf16x8*)&qrow[sh2 * 64 + s * 32 + quad * 8];
  }

  const f32x4 fz = {0.f, 0.f, 0.f, 0.f};
  f32x4 o1[8], o2[8];
  float rs1[4] = {0, 0, 0, 0}, rs2[4] = {0, 0, 0, 0};
#pragma unroll
  for (int i = 0; i < 8; ++i) { o1[i] = fz; o2[i] = fz; }

  const int xs = l15 & 7;

  for (int kt = 0; kt <= bx; ++kt) {
    const int cur = kt & 1;
    // __syncthreads drains vmcnt(0): tile kt (issued last iter / prologue) is
    // resident for ALL waves, and all waves finished reading buf[cur^1].
    __syncthreads();
    if (kt < bx) {                         // issue next tile into the freed buffer
      const int nb = cur ^ 1;
      const bf16_t* s1 = k1g + (size_t)(kt + 1) * 65536;
      const bf16_t* s2 = k2g + (size_t)(kt + 1) * 65536;
      const bf16_t* sv = vg + (size_t)(kt + 1) * 64;
      ldsload16(s1,         &k1s[nb][w * 1024]);
      ldsload16(s1 + 8192,  &k1s[nb][w * 1024 + 512]);
      ldsload16(s2,         &k2s[nb][w * 1024]);
      ldsload16(s2 + 8192,  &k2s[nb][w * 1024 + 512]);
      ldsload16(sv,         &vts[nb][w * 2048]);
      ldsload16(sv + 16384, &vts[nb][w * 2048 + 512]);
      ldsload16(sv + 32768, &vts[nb][w * 2048 + 1024]);
      ldsload16(sv + 49152, &vts[nb][w * 2048 + 1536]);
    }
    const int k0 = kt * 64;
    const bool diag = (kt == bx);

    bf16x8 pa1[2], pa2[2];
    qk_sm_fm(&k1s[cur][0], ps[w], q1f, rs1, pa1, diag, k0, q0, w, l15, quad);
    qk_sm_fm(&k2s[cur][0], ps[w], q2f, rs2, pa2, diag, k0, q0, w, l15, quad);

    // O += P(16x64) @ V(64x128), both components off one V read
    __builtin_amdgcn_s_setprio(1);
#pragma unroll
    for (int s = 0; s < 2; ++s) {
#pragma unroll
      for (int nt2 = 0; nt2 < 8; ++nt2) {
        bf16x8 vb = *(const bf16x8*)&vts[cur][(nt2 * 16 + l15) * 64 + ((((s << 2) + quad) ^ xs) << 3)];
        o1[nt2] = mfma16(pa1[s], vb, o1[nt2]);
        o2[nt2] = mfma16(pa2[s], vb, o2[nt2]);
      }
    }
    __builtin_amdgcn_s_setprio(0);
  }

  // epilogue: single shuffle-reduce of row sums, then diff + LN + store
#pragma unroll
  for (int mm = 1; mm <= 8; mm <<= 1)
#pragma unroll
    for (int r = 0; r < 4; ++r) { rs1[r] += __shfl_xor(rs1[r], mm); rs2[r] += __shfl_xor(rs2[r], mm); }
  float i1[4], i2[4];
#pragma unroll
  for (int r = 0; r < 4; ++r) { i1[r] = 1.f / rs1[r]; i2[r] = 1.f / rs2[r]; }
  f32x4 od[8];
  float sum[4] = {0, 0, 0, 0}, sq[4] = {0, 0, 0, 0};
#pragma unroll
  for (int nt2 = 0; nt2 < 8; ++nt2)
#pragma unroll
    for (int r = 0; r < 4; ++r) {
      float v = declamp(o1[nt2][r] * i1[r] - lam * o2[nt2][r] * i2[r], 1e4f);
      od[nt2][r] = v;
      sum[r] += v;
      sq[r] += v * v;
    }
#pragma unroll
  for (int mm = 1; mm <= 8; mm <<= 1)
#pragma unroll
    for (int r = 0; r < 4; ++r) { sum[r] += __shfl_xor(sum[r], mm); sq[r] += __shfl_xor(sq[r], mm); }
  float mu[4], scl[4];
#pragma unroll
  for (int r = 0; r < 4; ++r) {
    mu[r] = sum[r] * (1.0f / 128.0f);
    float var = sq[r] * (1.0f / 128.0f) - mu[r] * mu[r];
    scl[r] = rsqrtf(fmaxf(var, 0.f) + LN_EPS) * ONE_MINUS_LI;
  }
#pragma unroll
  for (int nt2 = 0; nt2 < 8; ++nt2)
#pragma unroll
    for (int r = 0; r < 4; ++r) {
      int trow = q0 + w * 16 + quad * 4 + r;
      outp[(bT + trow) * 1024 + h * 128 + nt2 * 16 + l15] =
          (bf16_t)((od[nt2][r] - mu[r]) * scl[r]);
    }
}

// ==================== FALLBACK PATH (round-4, zero ws) ====================

__device__ __forceinline__ void attn_step(
    const bf16_t* __restrict__ ks, bf16_t* __restrict__ pw, const bf16_t* __restrict__ vts,
    const bf16x8* qf, float* mR, float* lR, f32x4* o,
    bool diag, int k0, int q0, int w, int l15, int quad)
{
  f32x4 sc[4];
#pragma unroll
  for (int nt = 0; nt < 4; ++nt) {
    f32x4 a = {0.f, 0.f, 0.f, 0.f};
#pragma unroll
    for (int s = 0; s < 2; ++s) {
      bf16x8 b = *(const bf16x8*)&ks[(nt * 16 + l15) * 72 + s * 32 + quad * 8];
      a = mfma16(qf[s], b, a);
    }
#pragma unroll
    for (int r = 0; r < 4; ++r) a[r] = declamp(a[r], 1e4f);
    sc[nt] = a;
  }
  if (diag) {
#pragma unroll
    for (int nt = 0; nt < 4; ++nt)
#pragma unroll
      for (int r = 0; r < 4; ++r) {
        int col = k0 + nt * 16 + l15;
        int row = q0 + w * 16 + quad * 4 + r;
        if (col > row) sc[nt][r] = -1e30f;
      }
  }
  float mx[4];
#pragma unroll
  for (int r = 0; r < 4; ++r)
    mx[r] = fmaxf(fmaxf(sc[0][r], sc[1][r]), fmaxf(sc[2][r], sc[3][r]));
#pragma unroll
  for (int mm = 1; mm <= 8; mm <<= 1)
#pragma unroll
    for (int r = 0; r < 4; ++r) mx[r] = fmaxf(mx[r], __shfl_xor(mx[r], mm));

  float mnew[4], alpha[4], rs[4];
#pragma unroll
  for (int r = 0; r < 4; ++r) {
    mnew[r] = fmaxf(mR[r], mx[r]);
    alpha[r] = __expf(mR[r] - mnew[r]);
    rs[r] = 0.f;
  }
#pragma unroll
  for (int nt = 0; nt < 4; ++nt)
#pragma unroll
    for (int r = 0; r < 4; ++r) {
      float pv = __expf(sc[nt][r] - mnew[r]);
      rs[r] += pv;
      pw[(quad * 4 + r) * 72 + nt * 16 + l15] = (bf16_t)pv;
    }
#pragma unroll
  for (int mm = 1; mm <= 8; mm <<= 1)
#pragma unroll
    for (int r = 0; r < 4; ++r) rs[r] += __shfl_xor(rs[r], mm);
#pragma unroll
  for (int r = 0; r < 4; ++r) {
    lR[r] = lR[r] * alpha[r] + rs[r];
    mR[r] = mnew[r];
  }
#pragma unroll
  for (int nt2 = 0; nt2 < 8; ++nt2)
#pragma unroll
    for (int r = 0; r < 4; ++r) o[nt2][r] *= alpha[r];
#pragma unroll
  for (int s = 0; s < 2; ++s) {
    bf16x8 pa = *(const bf16x8*)&pw[l15 * 72 + s * 32 + quad * 8];
#pragma unroll
    for (int nt2 = 0; nt2 < 8; ++nt2) {
      bf16x8 vb = *(const bf16x8*)&vts[(nt2 * 16 + l15) * 72 + s * 32 + quad * 8];
      o[nt2] = mfma16(pa, vb, o[nt2]);
    }
  }
}

template<bool A_F32, bool OUT_F32>
__global__ __launch_bounds__(256) void gemm_bt(
    const void* __restrict__ Ap,
    const float* __restrict__ W0, const float* __restrict__ W1, const float* __restrict__ W2,
    void* __restrict__ Cp0, void* __restrict__ Cp1, void* __restrict__ Cp2)
{
  const float* W = (blockIdx.z == 0) ? W0 : ((blockIdx.z == 1) ? W1 : W2);
  void*       Cv = (blockIdx.z == 0) ? Cp0 : ((blockIdx.z == 1) ? Cp1 : Cp2);
  const int K = C_EMB, N = C_EMB;
  const int n0 = blockIdx.x * 128, m0 = blockIdx.y * 128;
  __shared__ bf16_t As[128 * 40];
  __shared__ bf16_t Bs[128 * 40];
  const int tid = threadIdx.x;
  const int lane = tid & 63, w = tid >> 6;
  const int wm = w >> 1, wn = w & 1;
  const int l15 = lane & 15, quad = lane >> 4;
  const f32x4 fz = {0.f, 0.f, 0.f, 0.f};
  f32x4 acc[4][4];
#pragma unroll
  for (int i = 0; i < 4; ++i)
#pragma unroll
    for (int j = 0; j < 4; ++j) acc[i][j] = fz;

  for (int k0 = 0; k0 < K; k0 += 32) {
    if constexpr (A_F32) {
      const float* Af = (const float*)Ap;
#pragma unroll
      for (int i = 0; i < 4; ++i) {
        int c = tid + i * 256;
        int r = c >> 3, c4 = (c & 7) * 4;
        f32x4 v = *(const f32x4*)&Af[(size_t)(m0 + r) * K + k0 + c4];
        bf16x4 bv;
#pragma unroll
        for (int j = 0; j < 4; ++j) bv[j] = (bf16_t)v[j];
        *(bf16x4*)&As[r * 40 + c4] = bv;
      }
    } else {
      const bf16_t* Ab = (const bf16_t*)Ap;
#pragma unroll
      for (int i = 0; i < 2; ++i) {
        int c = tid + i * 256;
        int r = c >> 2, c8 = (c & 3) * 8;
        *(bf16x8*)&As[r * 40 + c8] = *(const bf16x8*)&Ab[(size_t)(m0 + r) * K + k0 + c8];
      }
    }
#pragma unroll
    for (int i = 0; i < 4; ++i) {
      int c = tid + i * 256;
      int r = c >> 3, c4 = (c & 7) * 4;
      f32x4 v = *(const f32x4*)&W[(size_t)(n0 + r) * K + k0 + c4];
      bf16x4 bv;
#pragma unroll
      for (int j = 0; j < 4; ++j) bv[j] = (bf16_t)v[j];
      *(bf16x4*)&Bs[r * 40 + c4] = bv;
    }
    __syncthreads();
    bf16x8 af[4], bfr[4];
#pragma unroll
    for (int i = 0; i < 4; ++i)
      af[i] = *(const bf16x8*)&As[(wm * 64 + i * 16 + l15) * 40 + quad * 8];
#pragma unroll
    for (int j = 0; j < 4; ++j)
      bfr[j] = *(const bf16x8*)&Bs[(wn * 64 + j * 16 + l15) * 40 + quad * 8];
#pragma unroll
    for (int i = 0; i < 4; ++i)
#pragma unroll
      for (int j = 0; j < 4; ++j) acc[i][j] = mfma16(af[i], bfr[j], acc[i][j]);
    __syncthreads();
  }
#pragma unroll
  for (int i = 0; i < 4; ++i)
#pragma unroll
    for (int j = 0; j < 4; ++j)
#pragma unroll
      for (int r = 0; r < 4; ++r) {
        int row = m0 + wm * 64 + i * 16 + quad * 4 + r;
        int col = n0 + wn * 64 + j * 16 + l15;
        float v = declamp(acc[i][j][r], 1e4f);
        if constexpr (OUT_F32) ((float*)Cv)[(size_t)row * N + col] = v;
        else                   ((bf16_t*)Cv)[(size_t)row * N + col] = (bf16_t)v;
      }
}

__global__ __launch_bounds__(256) void rope_rms(bf16_t* __restrict__ arr, int is_q)
{
  const int tid = threadIdx.x;
  const int g = blockIdx.x * 16 + (tid >> 4);
  const int l16 = tid & 15;
  const int t = (g >> 4) & (T_SEQ - 1);
  bf16_t* p = arr + (size_t)g * 64 + l16 * 4;
  bf16x4 xv = *(const bf16x4*)p;
  float x[4];
#pragma unroll
  for (int j = 0; j < 4; ++j) x[j] = (float)xv[j];
  float ss = x[0]*x[0] + x[1]*x[1] + x[2]*x[2] + x[3]*x[3];
#pragma unroll
  for (int mm = 1; mm <= 8; mm <<= 1) ss += __shfl_xor(ss, mm);
  const float rn = rsqrtf(fmaxf(ss, 0.f) * (1.0f / 64.0f) + RMS_EPS);
  float nrm[4], prt[4];
#pragma unroll
  for (int j = 0; j < 4; ++j) nrm[j] = x[j] * rn;
#pragma unroll
  for (int j = 0; j < 4; ++j) prt[j] = __shfl_xor(nrm[j], 8);
  const int ib = (l16 & 7) * 4;
  const float sgn = (l16 < 8) ? 1.f : -1.f;
  const float scale = is_q ? 0.125f : 1.0f;
  bf16x4 ov;
#pragma unroll
  for (int j = 0; j < 4; ++j) {
    int i = ib + j;
    float invf = __expf(-(float)i * 0.28782313662425575f);
    float ang = (float)t * invf;
    float c, s;
    __sincosf(ang, &s, &c);
    ov[j] = (bf16_t)((nrm[j] * c + sgn * prt[j] * s) * scale);
  }
  *(bf16x4*)p = ov;
}

__global__ __launch_bounds__(256) void diff_attn(
    const bf16_t* qp, const bf16_t* __restrict__ kp, const bf16_t* __restrict__ vp,
    const float* __restrict__ lq1, const float* __restrict__ lk1,
    const float* __restrict__ lq2, const float* __restrict__ lk2,
    bf16_t* outp)
{
  const int bx = blockIdx.x;
  const int h = blockIdx.y;
  const int q0 = bx * 64;
  const int tid = threadIdx.x;
  const int lane = tid & 63, w = tid >> 6;
  const int l15 = lane & 15, quad = lane >> 4;

  __shared__ bf16_t k1s[64 * 72];
  __shared__ bf16_t k2s[64 * 72];
  __shared__ bf16_t vts[128 * 72];
  __shared__ bf16_t ps[4][16 * 72];

  float e1 = lq1[lane] * lk1[lane];
  float e2 = lq2[lane] * lk2[lane];
#pragma unroll
  for (int mm = 1; mm <= 32; mm <<= 1) { e1 += __shfl_xor(e1, mm); e2 += __shfl_xor(e2, mm); }
  const float lam = expf(declamp(e1, 30.f)) - expf(declamp(e2, 30.f)) + LAMBDA_INIT;

  const int sh1 = 2 * h, sh2 = 2 * h + 1;
  const int tq = q0 + w * 16 + l15;
  const bf16_t* qrow = qp + (size_t)tq * 1024;
  bf16x8 q1f[2], q2f[2];
#pragma unroll
  for (int s = 0; s < 2; ++s) {
    q1f[s] = *(const bf16x8*)&qrow[sh1 * 64 + s * 32 + quad * 8];
    q2f[s] = *(const bf16x8*)&qrow[sh2 * 64 + s * 32 + quad * 8];
  }
  const f32x4 fz = {0.f, 0.f, 0.f, 0.f};
  f32x4 o1[8], o2[8];
  float m1[4], l1[4], m2[4], l2[4];
#pragma unroll
  for (int i = 0; i < 8; ++i) { o1[i] = fz; o2[i] = fz; }
#pragma unroll
  for (int r = 0; r < 4; ++r) { m1[r] = -1e30f; m2[r] = -1e30f; l1[r] = 0.f; l2[r] = 0.f; }

  for (int kt = 0; kt <= bx; ++kt) {
    const int k0 = kt * 64;
    __syncthreads();
#pragma unroll
    for (int i = 0; i < 2; ++i) {
      int c = tid + i * 256;
      int r = c >> 3, c8 = (c & 7) * 8;
      const bf16_t* krow = kp + (size_t)(k0 + r) * 1024;
      *(bf16x8*)&k1s[r * 72 + c8] = *(const bf16x8*)&krow[sh1 * 64 + c8];
      *(bf16x8*)&k2s[r * 72 + c8] = *(const bf16x8*)&krow[sh2 * 64 + c8];
    }
#pragma unroll
    for (int i = 0; i < 4; ++i) {
      int c = tid + i * 256;
      int r = c >> 4, d8 = (c & 15) * 8;
      bf16x8 vv = *(const bf16x8*)&vp[(size_t)(k0 + r) * 1024 + h * 128 + d8];
#pragma unroll
      for (int jj = 0; jj < 8; ++jj) vts[(d8 + jj) * 72 + r] = vv[jj];
    }
    __syncthreads();
    const bool diag = (kt == bx);
    attn_step(k1s, ps[w], vts, q1f, m1, l1, o1, diag, k0, q0, w, l15, quad);
    attn_step(k2s, ps[w], vts, q2f, m2, l2, o2, diag, k0, q0, w, l15, quad);
  }
  float i1[4], i2[4];
#pragma unroll
  for (int r = 0; r < 4; ++r) { i1[r] = 1.f / l1[r]; i2[r] = 1.f / l2[r]; }
  f32x4 od[8];
  float sum[4] = {0, 0, 0, 0}, sq[4] = {0, 0, 0, 0};
#pragma unroll
  for (int nt2 = 0; nt2 < 8; ++nt2)
#pragma unroll
    for (int r = 0; r < 4; ++r) {
      float v = declamp(o1[nt2][r] * i1[r] - lam * o2[nt2][r] * i2[r], 1e4f);
      od[nt2][r] = v;
      sum[r] += v;
      sq[r] += v * v;
    }
#pragma unroll
  for (int mm = 1; mm <= 8; mm <<= 1)
#pragma unroll
    for (int r = 0; r < 4; ++r) { sum[r] += __shfl_xor(sum[r], mm); sq[r] += __shfl_xor(sq[r], mm); }
  float mu[4], scl[4];
#pragma unroll
  for (int r = 0; r < 4; ++r) {
    mu[r] = sum[r] * (1.0f / 128.0f);
    float var = sq[r] * (1.0f / 128.0f) - mu[r] * mu[r];
    scl[r] = rsqrtf(fmaxf(var, 0.f) + LN_EPS) * ONE_MINUS_LI;
  }
#pragma unroll
  for (int nt2 = 0; nt2 < 8; ++nt2)
#pragma unroll
    for (int r = 0; r < 4; ++r) {
      int trow = q0 + w * 16 + quad * 4 + r;
      outp[(size_t)trow * 1024 + h * 128 + nt2 * 16 + l15] =
          (bf16_t)((od[nt2][r] - mu[r]) * scl[r]);
    }
}

// ==================== launch ====================
extern "C" void kernel_launch(void* const* d_in, const int* in_sizes, int n_in,
                              void* d_out, int out_size, void* d_ws, size_t ws_size,
                              hipStream_t stream) {
  const float* x     = (const float*)d_in[0];
  const float* Wq    = (const float*)d_in[1];
  const float* Wk    = (const float*)d_in[2];
  const float* Wv    = (const float*)d_in[3];
  const float* Wproj = (const float*)d_in[4];
  const float* lq1   = (const float*)d_in[5];
  const float* lk1   = (const float*)d_in[6];
  const float* lq2   = (const float*)d_in[7];
  const float* lk2   = (const float*)d_in[8];
  float* O = (float*)d_out;
  const size_t R = (size_t)T_SEQ * C_EMB;

  if (ws_size >= (size_t)40 * 1024 * 1024) {
    // ---------- FAST PATH ----------
    bf16_t* wsb = (bf16_t*)d_ws;
    bf16_t* xb  = wsb;                       // [0, 8M elems) ; reused as attn-out
    bf16_t* wqb = wsb + 8388608;
    bf16_t* wkb = wqb + 1048576;
    bf16_t* wvb = wkb + 1048576;
    bf16_t* wpb = wvb + 1048576;
    bf16_t* vt  = wpb + 1048576;             // [12M, 20M elems) = 16MB
    bf16_t* qo  = (bf16_t*)d_out;            // d_out low half
    bf16_t* ko  = qo + 8388608;              // d_out high half
    bf16_t* a   = xb;                        // attn-out over dead xb

    cvt_all<<<12288, 256, 0, stream>>>(x, Wq, Wk, Wv, Wproj, xb, wqb, wkb, wvb, wpb);
    gemm_qkv<<<dim3(8, 64, 3), 256, 0, stream>>>(xb, wqb, wkb, wvb, qo, ko, vt);
    diff_attn2<<<dim3(32, 32), 256, 0, stream>>>(qo, ko, vt, lq1, lk1, lq2, lk2, a);
    gemm_proj<<<dim3(8, 64), 256, 0, stream>>>(a, wpb, O);
  } else {
    // ---------- FALLBACK (round-4 proven, zero ws) ----------
    char* Ob = (char*)d_out;
    char* Xb = (char*)d_in[0];
    const size_t MB4 = (size_t)1 << 22;
    bf16_t* qb[4] = { (bf16_t*)(Ob + 2*MB4), (bf16_t*)(Ob + 5*MB4),
                      (bf16_t*)(Xb + 0*MB4), (bf16_t*)(Xb + 3*MB4) };
    bf16_t* kb[4] = { (bf16_t*)(Ob + 3*MB4), (bf16_t*)(Ob + 6*MB4),
                      (bf16_t*)(Xb + 1*MB4), (bf16_t*)(Xb + 4*MB4) };
    bf16_t* vb[4] = { (bf16_t*)(Ob + 4*MB4), (bf16_t*)(Ob + 7*MB4),
                      (bf16_t*)(Xb + 2*MB4), (bf16_t*)(Xb + 5*MB4) };
    for (int b = 0; b < 4; ++b) {
      const float* xbp = x + (size_t)b * R;
      gemm_bt<true, false><<<dim3(8, 16, 3), 256, 0, stream>>>(
          xbp, Wq, Wk, Wv, qb[b], kb[b], vb[b]);
      rope_rms<<<2048, 256, 0, stream>>>(qb[b], 1);
      rope_rms<<<2048, 256, 0, stream>>>(kb[b], 0);
      diff_attn<<<dim3(32, 8), 256, 0, stream>>>(qb[b], kb[b], vb[b],
                                                 lq1, lk1, lq2, lk2, qb[b]);
      gemm_bt<false, true><<<dim3(8, 16, 1), 256, 0, stream>>>(
          qb[b], Wproj, Wproj, Wproj, O + (size_t)b * R, nullptr, nullptr);
    }
  }
}